// Round 8
// baseline (4864.328 us; speedup 1.0000x reference)
//
#include <hip/hip_runtime.h>
#include <math.h>

// stacked_rnn R14: R13 (rebalanced + barrier-fill, 3548us proven) with the
// per-epoch acquire fence REMOVED. Evidence: FETCH=858MB vs ~90MB inputs and
// WRITE=790MB == write-through volume -> the every-epoch agent-acquire fence
// (whole-XCD L2 invalidate, repeatedly re-nuked by 32 async blocks/XCD) was
// defeating all cache reuse. Replacement: all cross-block-communicated reads
// (h1/h2 A-streams, p slices) use agent-scope RELAXED ATOMIC loads (8B pairs)
// which observe the coherence point directly — the same mechanism the flag
// polls already use successfully. x/weights stay L2-warm. One fence retained
// after the loop for the FC's plain reads. Store protocol unchanged
// (relaxed-agent write-through + vmcnt(0) before arrive).
// Fallback chain unchanged: ws-size guard + proven R10 8-wave kernel (fence-based).

typedef __bf16 bf16;
typedef __bf16 bf16x8 __attribute__((ext_vector_type(8)));
typedef float floatx4 __attribute__((ext_vector_type(4)));
typedef unsigned long long ull;

#define B_   128
#define T_   256
#define H_   1024
#define I_   150
#define KX_  160
#define C_   60
#define K1LDS 1280   // L0 W1 LDS row width in elems (x 160 + h1 1024 + pad)
#define KP    1024   // Wih2 / Whh2 LDS row width
#define K2LDS 2048   // fallback kernel layer-2 row width
#define NLINES 32    // zeroed counter lines (primary uses 0..15 + flag @16;
                     // fallback uses 0..7 + flag @8)
#define CSTRIDE 64   // uints between lines (256B)
#define FLAGLINE 16
#define NCOLS 32     // gate-cols per block tile
#define NHC  8       // h-cols per block (NCOLS/4)
#define NT   2       // N-tiles of 16

template<int N> struct IC { static constexpr int value = N; };

__device__ __forceinline__ float sigmoidf_(float x) { return 1.f / (1.f + expf(-x)); }

union U16B { ull u[2]; bf16x8 v; };

// coherent 16B load: two 8B agent-scope relaxed atomic loads (bypass stale L1/L2)
__device__ __forceinline__ bf16x8 loadH16(const bf16* p) {
    U16B x;
    x.u[0] = __hip_atomic_load((const ull*)p,     __ATOMIC_RELAXED, __HIP_MEMORY_SCOPE_AGENT);
    x.u[1] = __hip_atomic_load((const ull*)p + 1, __ATOMIC_RELAXED, __HIP_MEMORY_SCOPE_AGENT);
    return x.v;
}

// ---------------- conversion / init kernel ----------------
__global__ __launch_bounds__(256)
void convert_all(const float* __restrict__ x,
                 const float* __restrict__ h1in, const float* __restrict__ h2in,
                 bf16* __restrict__ xb, bf16* __restrict__ h1b0, bf16* __restrict__ h2b0,
                 unsigned* __restrict__ cnt)
{
    const size_t nXB = (size_t)T_ * B_ * KX_;   // 5242880
    const size_t nHC = (size_t)B_ * H_;         // 131072
    size_t idx = (size_t)blockIdx.x * 256 + threadIdx.x;

    if (idx < nXB) {                            // x [B][T][150] -> xb [T][B][160]
        size_t t = idx / (B_ * KX_);
        size_t r = idx - t * (B_ * KX_);
        size_t b = r / KX_, k = r - b * KX_;
        xb[idx] = (k < I_) ? (bf16)x[(b * T_ + t) * I_ + k] : (bf16)0.f;
        return;
    }
    idx -= nXB;
    if (idx < nHC) { h1b0[idx] = (bf16)h1in[idx]; return; }
    idx -= nHC;
    if (idx < nHC) { h2b0[idx] = (bf16)h2in[idx]; return; }
    idx -= nHC;
    if (idx < NLINES * CSTRIDE) cnt[idx] = 0u;
}

// ================= R14 primary: 8-wave rebalanced, fence-free loop ==========
// 256 blocks = 2 layers x 128 slices. layer=(bid>>3)&1, slice=(bid&7)|((bid>>4)<<3).
// L0: LDS = W1 (32x1280) + Wih2 slice (32x1024) = 144KB. epoch e in [0,T_]:
//   acc preloaded with x(e) part (overlapped into barrier e-1, cached loads);
//   dual-seg h1(e) via COHERENT loads -> gates1 + p(e); publish; epilogue.
// L1: LDS = Whh2 slice (32x1024) = 64KB. epoch e in [2,T_+1]:
//   coherent-prefetch p(e-1); coherent-stream h2(e-2); epilogue h2(e-1).
__global__ __launch_bounds__(512, 2)
void rnn_rebal8(const bf16* __restrict__ xb,
                bf16* __restrict__ h1b0, bf16* __restrict__ h1b1,
                bf16* __restrict__ h2b0, bf16* __restrict__ h2b1,
                float* __restrict__ p0, float* __restrict__ p1,
                const float* __restrict__ c1in, const float* __restrict__ c2in,
                const float* __restrict__ Wih1, const float* __restrict__ Whh1,
                const float* __restrict__ bih1, const float* __restrict__ bhh1,
                const float* __restrict__ Wih2, const float* __restrict__ Whh2,
                const float* __restrict__ bih2, const float* __restrict__ bhh2,
                const float* __restrict__ Wfc, const float* __restrict__ bfc,
                float* __restrict__ out, unsigned* __restrict__ cnt, int nblk)
{
    extern __shared__ bf16 lds[];
    __shared__ __align__(16) bf16 hst[8][16][NHC];   // epilogue staging

    const int tid   = threadIdx.x;
    const int bid   = blockIdx.x;
    const int layer = (bid >> 3) & 1;
    const int slice = (bid & 7) | ((bid >> 4) << 3);
    const int n0h   = slice * NHC;
    const int arr_per_line = nblk >> 4;          // 16 lines x 16 blocks
    bf16* ldsP = lds + 32 * K1LDS;               // L0's Wih2 region

    // ---- stage weights fp32->bf16 into swizzled LDS (once) ----
    if (layer == 0) {
        {   // W1 region: 32 rows x K1LDS (x [0,160), h1 [160,1184), pad)
            const int cpr = K1LDS >> 3;           // 160
            const int total = NCOLS * cpr;
            for (int ci = tid; ci < total; ci += 512) {
                int r = ci / cpr, c = ci - r * cpr;
                int g = r / NHC, j = r - g * NHC;
                int grow = (g << 10) + n0h + j;
                int k0 = c << 3;
                float v[8];
#pragma unroll
                for (int u = 0; u < 8; ++u) {
                    int k = k0 + u;
                    v[u] = (k < I_) ? Wih1[(size_t)grow * I_ + k]
                         : (k < KX_) ? 0.f
                         : (k < KX_ + H_) ? Whh1[(size_t)grow * H_ + (k - KX_)] : 0.f;
                }
                int cs = (c & ~15) | ((c ^ r) & 15);
                bf16* dst = lds + (size_t)r * K1LDS + (cs << 3);
#pragma unroll
                for (int u = 0; u < 8; ++u) dst[u] = (bf16)v[u];
            }
        }
        {   // Wih2 region: 32 rows x KP
            const int cpr = KP >> 3;              // 128
            const int total = NCOLS * cpr;
            for (int ci = tid; ci < total; ci += 512) {
                int r = ci / cpr, c = ci - r * cpr;
                int g = r / NHC, j = r - g * NHC;
                int grow = (g << 10) + n0h + j;
                int k0 = c << 3;
                float v[8];
#pragma unroll
                for (int u = 0; u < 8; ++u) v[u] = Wih2[(size_t)grow * H_ + k0 + u];
                int cs = (c & ~15) | ((c ^ r) & 15);
                bf16* dst = ldsP + (size_t)r * KP + (cs << 3);
#pragma unroll
                for (int u = 0; u < 8; ++u) dst[u] = (bf16)v[u];
            }
        }
    } else {
        // Whh2 region: 32 rows x KP
        const int cpr = KP >> 3;
        const int total = NCOLS * cpr;
        for (int ci = tid; ci < total; ci += 512) {
            int r = ci / cpr, c = ci - r * cpr;
            int g = r / NHC, j = r - g * NHC;
            int grow = (g << 10) + n0h + j;
            int k0 = c << 3;
            float v[8];
#pragma unroll
            for (int u = 0; u < 8; ++u) v[u] = Whh2[(size_t)grow * H_ + k0 + u];
            int cs = (c & ~15) | ((c ^ r) & 15);
            bf16* dst = lds + (size_t)r * KP + (cs << 3);
#pragma unroll
            for (int u = 0; u < 8; ++u) dst[u] = (bf16)v[u];
        }
    }
    __syncthreads();

    const int lane = tid & 63;
    const int wv   = tid >> 6;          // 0..7
    const int jj   = lane & (NHC - 1);
    const int quad = lane >> 4;

    float4 bias;
    {
        const float* bi = layer ? bih2 : bih1;
        const float* bh = layer ? bhh2 : bhh1;
        int col = n0h + jj;
        bias.x = bi[col] + bh[col];
        bias.y = bi[col + H_] + bh[col + H_];
        bias.z = bi[col + 2 * H_] + bh[col + 2 * H_];
        bias.w = bi[col + 3 * H_] + bh[col + 3 * H_];
    }

    float creg[2];
    {
        const float* cin = layer ? c2in : c1in;
        int dup = (lane >> 3) & 1;
#pragma unroll
        for (int rp = 0; rp < 2; ++rp) {
            int row = wv * 16 + quad * 4 + rp * 2 + dup;
            creg[rp] = cin[(size_t)row * H_ + n0h + jj];
        }
    }

    floatx4 acc[NT];
    floatx4 pacc[NT];

    // x K-segment: plain cached loads (immutable input, stays L2-warm)
    auto segX = [&](const bf16* A) {
        const int arow = wv * 16 + (lane & 15);
        const bf16* a0 = A + (size_t)arow * KX_ + quad * 8;
        bf16x8 a0r[5];
#pragma unroll
        for (int i = 0; i < 5; ++i)
            a0r[i] = *(const bf16x8*)(a0 + i * 32);
        __builtin_amdgcn_sched_barrier(0);
#pragma unroll
        for (int i = 0; i < 5; ++i) {
            int c = i * 4 + quad;
#pragma unroll
            for (int t = 0; t < NT; ++t) {
                int r = t * 16 + (lane & 15);
                int cs = (c & ~15) | ((c ^ r) & 15);
                bf16x8 bfr = *(const bf16x8*)(lds + (size_t)r * K1LDS + (cs << 3));
                acc[t] = __builtin_amdgcn_mfma_f32_16x16x32_bf16(a0r[i], bfr, acc[t], 0, 0, 0);
            }
        }
    };

    // h2 K-segment (L1): coherent loads, single target
    auto segH2 = [&](const bf16* A) {
        const int arow = wv * 16 + (lane & 15);
        const bf16* a0 = A + (size_t)arow * H_ + quad * 8;
        for (int blk = 0; blk < 32; blk += 16) {
            bf16x8 a0r[16];
#pragma unroll
            for (int i = 0; i < 16; ++i)
                a0r[i] = loadH16(a0 + (blk + i) * 32);
            __builtin_amdgcn_sched_barrier(0);
#pragma unroll
            for (int i = 0; i < 16; ++i) {
                int c = (blk + i) * 4 + quad;
#pragma unroll
                for (int t = 0; t < NT; ++t) {
                    int r = t * 16 + (lane & 15);
                    int cs = (c & ~15) | ((c ^ r) & 15);
                    bf16x8 bfr = *(const bf16x8*)(lds + (size_t)r * KP + (cs << 3));
                    acc[t] = __builtin_amdgcn_mfma_f32_16x16x32_bf16(a0r[i], bfr, acc[t], 0, 0, 0);
                }
            }
        }
    };

    // dual-target h1-segment (L0): coherent loads; gates1 into acc (W1,
    // ksBase 5) AND p into pacc (Wih2, ksBase 0) from the SAME A stream.
    auto segDual = [&](const bf16* A) {
        const int arow = wv * 16 + (lane & 15);
        const bf16* a0 = A + (size_t)arow * H_ + quad * 8;
        for (int blk = 0; blk < 32; blk += 16) {
            bf16x8 a0r[16];
#pragma unroll
            for (int i = 0; i < 16; ++i)
                a0r[i] = loadH16(a0 + (blk + i) * 32);
            __builtin_amdgcn_sched_barrier(0);
#pragma unroll
            for (int i = 0; i < 16; ++i) {
                int ig = blk + i;
                int c1 = (5 + ig) * 4 + quad;
                int cp = ig * 4 + quad;
#pragma unroll
                for (int t = 0; t < NT; ++t) {
                    int r = t * 16 + (lane & 15);
                    int cs1 = (c1 & ~15) | ((c1 ^ r) & 15);
                    bf16x8 b1 = *(const bf16x8*)(lds + (size_t)r * K1LDS + (cs1 << 3));
                    acc[t] = __builtin_amdgcn_mfma_f32_16x16x32_bf16(a0r[i], b1, acc[t], 0, 0, 0);
                    int csp = (cp & ~15) | ((cp ^ r) & 15);
                    bf16x8 bp = *(const bf16x8*)(ldsP + (size_t)r * KP + (csp << 3));
                    pacc[t] = __builtin_amdgcn_mfma_f32_16x16x32_bf16(a0r[i], bp, pacc[t], 0, 0, 0);
                }
            }
        }
    };

    // epilogue: shfl-gather gates, update creg, stage h to LDS, store h
    auto epilogue = [&](bf16* hw) {
        const int base = lane & 48;
#pragma unroll
        for (int r = 0; r < 4; ++r) {
            float vi = __shfl(acc[0][r], base + jj, 64);
            float vf = __shfl(acc[0][r], base + 8 + jj, 64);
            float vg = __shfl(acc[1][r], base + jj, 64);
            float vo = __shfl(acc[1][r], base + 8 + jj, 64);
            bool cond = (((lane >> 3) & 1) == (r & 1));
            int slot = r >> 1;
            if (cond) {
                float cv = creg[slot];
                float cn = sigmoidf_(vf + bias.y) * cv
                         + sigmoidf_(vi + bias.x) * tanhf(vg + bias.z);
                creg[slot] = cn;
                float hn = sigmoidf_(vo + bias.w) * tanhf(cn);
                hst[wv][quad * 4 + r][jj] = (bf16)hn;
            }
        }
        __syncthreads();
        if (lane < 32) {
            int row_l = lane >> 1, cg = lane & 1;
            ull v = *(const ull*)&hst[wv][row_l][cg * 4];
            __hip_atomic_store((ull*)(hw + (size_t)(wv * 16 + row_l) * H_ + n0h + cg * 4),
                               v, __ATOMIC_RELAXED, __HIP_MEMORY_SCOPE_AGENT);
        }
    };

    // prologue (L0): zero accs and pre-compute x(0) contribution
    if (layer == 0) {
#pragma unroll
        for (int t = 0; t < NT; ++t) {
            acc[t]  = (floatx4){0.f, 0.f, 0.f, 0.f};
            pacc[t] = (floatx4){0.f, 0.f, 0.f, 0.f};
        }
        segX(xb);                                  // x(0)
    }

    for (int e = 0; e <= T_ + 1; ++e) {
        if (layer == 0 && e <= T_) {
            // acc holds x(e) part (preloaded); dual-seg adds h1(e) part + p(e)
            const bf16* h1r = (e & 1) ? h1b1 : h1b0;          // h1^(e)
            segDual(h1r);

            // publish p(e) slice (f32, relaxed-agent write-through)
            float* pw = ((e & 1) ? p1 : p0) + (size_t)slice * B_ * NCOLS;
#pragma unroll
            for (int t = 0; t < NT; ++t)
#pragma unroll
                for (int r = 0; r < 4; ++r) {
                    int row = wv * 16 + quad * 4 + r;
                    __hip_atomic_store(pw + (size_t)row * NCOLS + t * 16 + (lane & 15),
                                       pacc[t][r], __ATOMIC_RELAXED, __HIP_MEMORY_SCOPE_AGENT);
                }

            if (e < T_) {
                bf16* hw = (e & 1) ? h1b0 : h1b1;              // h1^(e+1)
                epilogue(hw);
            }
        } else if (layer == 1 && e >= 2) {
#pragma unroll
            for (int t = 0; t < NT; ++t) acc[t] = (floatx4){0.f, 0.f, 0.f, 0.f};

            // coherent prefetch of p(e-1) slice into registers
            const float* pr = ((e & 1) ? p0 : p1) + (size_t)slice * B_ * NCOLS;
            float pv[NT][4];
#pragma unroll
            for (int t = 0; t < NT; ++t)
#pragma unroll
                for (int r = 0; r < 4; ++r) {
                    int row = wv * 16 + quad * 4 + r;
                    pv[t][r] = __hip_atomic_load(pr + (size_t)row * NCOLS + t * 16 + (lane & 15),
                                                 __ATOMIC_RELAXED, __HIP_MEMORY_SCOPE_AGENT);
                }

            const bf16* h2r = (e & 1) ? h2b1 : h2b0;           // h2^(e-2)
            segH2(h2r);

#pragma unroll
            for (int t = 0; t < NT; ++t)
#pragma unroll
                for (int r = 0; r < 4; ++r) acc[t][r] += pv[t][r];

            bf16* hw = (e & 1) ? h2b0 : h2b1;                  // h2^(e-1)
            epilogue(hw);
        }

        // ---- barrier: arrive -> overlapped x-prefetch (L0) -> detect (NO fence)
        asm volatile("s_waitcnt vmcnt(0)" ::: "memory");
        __syncthreads();
        const unsigned etag = (unsigned)(e + 1);
        if (tid == 0)
            __hip_atomic_fetch_add(cnt + (bid & 15) * CSTRIDE, 1u,
                                   __ATOMIC_RELAXED, __HIP_MEMORY_SCOPE_AGENT);
        // overlapped work in the barrier window: next-epoch x-seg on
        // immutable input (plain cached loads; L2 stays warm — no fence)
        if (layer == 0 && e < T_) {
#pragma unroll
            for (int t = 0; t < NT; ++t) {
                acc[t]  = (floatx4){0.f, 0.f, 0.f, 0.f};
                pacc[t] = (floatx4){0.f, 0.f, 0.f, 0.f};
            }
            if (e + 1 < T_)
                segX(xb + (size_t)(e + 1) * B_ * KX_);
        }
        if (bid == 0) {
            if (tid < 16) {
                const unsigned tgt = etag * (unsigned)arr_per_line;
                const unsigned* cp = cnt + tid * CSTRIDE;
                while (__hip_atomic_load(cp, __ATOMIC_RELAXED, __HIP_MEMORY_SCOPE_AGENT) < tgt)
                    __builtin_amdgcn_s_sleep(1);
            }
            if (tid == 0)
                __hip_atomic_store(cnt + FLAGLINE * CSTRIDE, etag,
                                   __ATOMIC_RELAXED, __HIP_MEMORY_SCOPE_AGENT);
        } else {
            if (tid == 0) {
                const unsigned* fp = cnt + FLAGLINE * CSTRIDE;
                while (__hip_atomic_load(fp, __ATOMIC_RELAXED, __HIP_MEMORY_SCOPE_AGENT) < etag)
                    __builtin_amdgcn_s_sleep(1);
            }
        }
        __syncthreads();
        // no per-epoch fence: all cross-block reads are coherent atomic loads
    }

    // single acquire fence before FC (h2b0 read with plain cached loads below)
    if (tid < 64)
        __builtin_amdgcn_fence(__ATOMIC_ACQUIRE, "agent");
    __syncthreads();

    // ---- fused FC: out = h2^(256) @ Wfc^T + bfc ; h2^(256) is in h2b0 ----
    if (bid < B_) {
        const bf16* h2f = h2b0;
        for (int c = wv; c < C_; c += 8) {
            float a = 0.f;
            for (int k = lane; k < H_; k += 64)
                a += (float)h2f[(size_t)bid * H_ + k] * Wfc[(size_t)c * H_ + k];
#pragma unroll
            for (int off = 32; off; off >>= 1) a += __shfl_down(a, off, 64);
            if (lane == 0) out[bid * C_ + c] = a + bfc[c];
        }
    }
}

// ============ fallback: PROVEN R10 8-wave kernel (5140us, passed) ===========
// Same signature as primary; p0/p1 unused. Original R6 dataflow, fence-based.
__global__ __launch_bounds__(512, 2)
void rnn_fallback8(const bf16* __restrict__ xb,
                   bf16* __restrict__ h1b0, bf16* __restrict__ h1b1,
                   bf16* __restrict__ h2b0, bf16* __restrict__ h2b1,
                   float* __restrict__ p0, float* __restrict__ p1,
                   const float* __restrict__ c1in, const float* __restrict__ c2in,
                   const float* __restrict__ Wih1, const float* __restrict__ Whh1,
                   const float* __restrict__ bih1, const float* __restrict__ bhh1,
                   const float* __restrict__ Wih2, const float* __restrict__ Whh2,
                   const float* __restrict__ bih2, const float* __restrict__ bhh2,
                   const float* __restrict__ Wfc, const float* __restrict__ bfc,
                   float* __restrict__ out, unsigned* __restrict__ cnt, int nblk)
{
    extern __shared__ bf16 lds[];
    __shared__ __align__(16) bf16 hst[8][16][NHC];

    const int tid   = threadIdx.x;
    const int bid   = blockIdx.x;
    const int layer = (bid >> 3) & 1;
    const int slice = (bid & 7) | ((bid >> 4) << 3);
    const int n0h   = slice * NHC;
    const int KLDS  = layer ? K2LDS : K1LDS;
    const int arr_per_line = nblk >> 3;

    {   // stage weights (R6 combined map)
        const int cpr = KLDS >> 3;
        const int total = NCOLS * cpr;
        for (int ci = tid; ci < total; ci += 512) {
            int r = ci / cpr, c = ci - r * cpr;
            int g = r / NHC, j = r - g * NHC;
            int grow = (g << 10) + n0h + j;
            int k0 = c << 3;
            float v[8];
#pragma unroll
            for (int u = 0; u < 8; ++u) {
                int k = k0 + u;
                if (layer == 0)
                    v[u] = (k < I_) ? Wih1[(size_t)grow * I_ + k]
                         : (k < KX_) ? 0.f
                         : (k < KX_ + H_) ? Whh1[(size_t)grow * H_ + (k - KX_)] : 0.f;
                else
                    v[u] = (k < H_) ? Wih2[(size_t)grow * H_ + k]
                                    : Whh2[(size_t)grow * H_ + (k - H_)];
            }
            int cs = (c & ~15) | ((c ^ r) & 15);
            bf16* dst = lds + (size_t)r * KLDS + (cs << 3);
#pragma unroll
            for (int u = 0; u < 8; ++u) dst[u] = (bf16)v[u];
        }
    }
    __syncthreads();

    const int lane = tid & 63;
    const int wv   = tid >> 6;
    const int jj   = lane & (NHC - 1);
    const int quad = lane >> 4;

    float4 bias;
    {
        const float* bi = layer ? bih2 : bih1;
        const float* bh = layer ? bhh2 : bhh1;
        int col = n0h + jj;
        bias.x = bi[col] + bh[col];
        bias.y = bi[col + H_] + bh[col + H_];
        bias.z = bi[col + 2 * H_] + bh[col + 2 * H_];
        bias.w = bi[col + 3 * H_] + bh[col + 3 * H_];
    }

    float creg[2];
    {
        const float* cin = layer ? c2in : c1in;
        int dup = (lane >> 3) & 1;
#pragma unroll
        for (int rp = 0; rp < 2; ++rp) {
            int row = wv * 16 + quad * 4 + rp * 2 + dup;
            creg[rp] = cin[(size_t)row * H_ + n0h + jj];
        }
    }

    floatx4 acc[NT];

    auto seg = [&](const bf16* A, int ldA, auto nksC, int ksBase) {
        constexpr int NKS = decltype(nksC)::value;
        constexpr int CH  = NKS < 16 ? NKS : 16;
        const int arow = wv * 16 + (lane & 15);
        const bf16* a0 = A + (size_t)arow * ldA + quad * 8;
        for (int blk = 0; blk < NKS; blk += CH) {
            bf16x8 a0r[CH];
#pragma unroll
            for (int i = 0; i < CH; ++i)
                a0r[i] = *(const bf16x8*)(a0 + (blk + i) * 32);
            __builtin_amdgcn_sched_barrier(0);
#pragma unroll
            for (int i = 0; i < CH; ++i) {
                int c = (ksBase + blk + i) * 4 + quad;
#pragma unroll
                for (int t = 0; t < NT; ++t) {
                    int r = t * 16 + (lane & 15);
                    int cs = (c & ~15) | ((c ^ r) & 15);
                    bf16x8 bfr = *(const bf16x8*)(lds + (size_t)r * KLDS + (cs << 3));
                    acc[t] = __builtin_amdgcn_mfma_f32_16x16x32_bf16(a0r[i], bfr, acc[t], 0, 0, 0);
                }
            }
        }
    };

    for (int e = 0; e <= T_; ++e) {
        const bool active = layer == 0 ? (e < T_) : (e >= 1);
        if (active) {
#pragma unroll
            for (int t = 0; t < NT; ++t) acc[t] = (floatx4){0.f, 0.f, 0.f, 0.f};

            const bf16* h1r = (e & 1) ? h1b1 : h1b0;
            if (layer == 0) {
                const bf16* xt = xb + (size_t)e * B_ * KX_;
                seg(xt, KX_, IC<5>{}, 0);
                seg(h1r, H_, IC<32>{}, 5);
            } else {
                const bf16* h2r = (e & 1) ? h2b0 : h2b1;
                seg(h1r, H_, IC<32>{}, 0);
                seg(h2r, H_, IC<32>{}, 32);
            }
            bf16* hw = (layer == 0) ? ((e & 1) ? h1b0 : h1b1)
                                    : ((e & 1) ? h2b1 : h2b0);

            const int base = lane & 48;
#pragma unroll
            for (int r = 0; r < 4; ++r) {
                float vi = __shfl(acc[0][r], base + jj, 64);
                float vf = __shfl(acc[0][r], base + 8 + jj, 64);
                float vg = __shfl(acc[1][r], base + jj, 64);
                float vo = __shfl(acc[1][r], base + 8 + jj, 64);
                bool cond = (((lane >> 3) & 1) == (r & 1));
                int slot = r >> 1;
                if (cond) {
                    float cv = creg[slot];
                    float cn = sigmoidf_(vf + bias.y) * cv
                             + sigmoidf_(vi + bias.x) * tanhf(vg + bias.z);
                    creg[slot] = cn;
                    float hn = sigmoidf_(vo + bias.w) * tanhf(cn);
                    hst[wv][quad * 4 + r][jj] = (bf16)hn;
                }
            }
            __syncthreads();
            if (lane < 32) {
                int row_l = lane >> 1, cg = lane & 1;
                ull v = *(const ull*)&hst[wv][row_l][cg * 4];
                __hip_atomic_store((ull*)(hw + (size_t)(wv * 16 + row_l) * H_ + n0h + cg * 4),
                                   v, __ATOMIC_RELAXED, __HIP_MEMORY_SCOPE_AGENT);
            }
        }

        asm volatile("s_waitcnt vmcnt(0)" ::: "memory");
        __syncthreads();
        const unsigned etag = (unsigned)(e + 1);
        if (bid == 0) {
            if (tid == 0)
                __hip_atomic_fetch_add(cnt, 1u, __ATOMIC_RELAXED, __HIP_MEMORY_SCOPE_AGENT);
            if (tid < 8) {
                const unsigned tgt = etag * (unsigned)arr_per_line;
                const unsigned* cp = cnt + tid * CSTRIDE;
                while (__hip_atomic_load(cp, __ATOMIC_RELAXED, __HIP_MEMORY_SCOPE_AGENT) < tgt)
                    __builtin_amdgcn_s_sleep(1);
            }
            if (tid == 0)
                __hip_atomic_store(cnt + 8 * CSTRIDE, etag,
                                   __ATOMIC_RELAXED, __HIP_MEMORY_SCOPE_AGENT);
        } else {
            if (tid == 0) {
                __hip_atomic_fetch_add(cnt + (bid & 7) * CSTRIDE, 1u,
                                       __ATOMIC_RELAXED, __HIP_MEMORY_SCOPE_AGENT);
                const unsigned* fp = cnt + 8 * CSTRIDE;
                while (__hip_atomic_load(fp, __ATOMIC_RELAXED, __HIP_MEMORY_SCOPE_AGENT) < etag)
                    __builtin_amdgcn_s_sleep(1);
            }
        }
        __syncthreads();
        if (tid < 64)
            __builtin_amdgcn_fence(__ATOMIC_ACQUIRE, "agent");
        __syncthreads();
    }

    if (bid < B_) {
        const bf16* h2f = h2b0;
        for (int c = wv; c < C_; c += 8) {
            float a = 0.f;
            for (int k = lane; k < H_; k += 64)
                a += (float)h2f[(size_t)bid * H_ + k] * Wfc[(size_t)c * H_ + k];
#pragma unroll
            for (int off = 32; off; off >>= 1) a += __shfl_down(a, off, 64);
            if (lane == 0) out[bid * C_ + c] = a + bfc[c];
        }
    }
}

extern "C" void kernel_launch(void* const* d_in, const int* in_sizes, int n_in,
                              void* d_out, int out_size, void* d_ws, size_t ws_size,
                              hipStream_t stream)
{
    const float* x    = (const float*)d_in[0];
    const float* h1in = (const float*)d_in[1];
    const float* c1in = (const float*)d_in[2];
    const float* h2in = (const float*)d_in[3];
    const float* c2in = (const float*)d_in[4];
    const float* Wih1 = (const float*)d_in[5];
    const float* Whh1 = (const float*)d_in[6];
    const float* bih1 = (const float*)d_in[7];
    const float* bhh1 = (const float*)d_in[8];
    const float* Wih2 = (const float*)d_in[9];
    const float* Whh2 = (const float*)d_in[10];
    const float* bih2 = (const float*)d_in[11];
    const float* bhh2 = (const float*)d_in[12];
    const float* Wfc  = (const float*)d_in[13];
    const float* bfc  = (const float*)d_in[14];
    float* out = (float*)d_out;

    // ws carve: base ~11.5MB always; p buffers (+4MB) only if ws fits
    const size_t szXB  = (size_t)T_ * B_ * KX_ * 2;        // 10485760
    const size_t szH   = (size_t)B_ * H_ * 2;              // 262144
    const size_t szCnt = (size_t)NLINES * CSTRIDE * 4;     // 8192
    const size_t szP   = (size_t)128 * B_ * NCOLS * 4;     // 2097152
    const size_t needBase  = szXB + 4 * szH + szCnt;
    const size_t needRebal = needBase + 2 * szP;

    char* p = (char*)d_ws;
    bf16* xb = (bf16*)p;    p += szXB;
    bf16* h1b0 = (bf16*)p;  p += szH;
    bf16* h1b1 = (bf16*)p;  p += szH;
    bf16* h2b0 = (bf16*)p;  p += szH;
    bf16* h2b1 = (bf16*)p;  p += szH;
    unsigned* cnt = (unsigned*)p;  p += szCnt;
    float* p0 = (float*)p;  p += szP;
    float* p1 = (float*)p;

    const size_t citems = (size_t)T_ * B_ * KX_ + 2 * (size_t)B_ * H_ + NLINES * CSTRIDE;
    convert_all<<<(int)((citems + 255) / 256), 256, 0, stream>>>(
        x, h1in, h2in, xb, h1b0, h2b0, cnt);

    int nblk = 256;
    void* args[] = { &xb, &h1b0, &h1b1, &h2b0, &h2b1, &p0, &p1,
                     (void*)&c1in, (void*)&c2in,
                     (void*)&Wih1, (void*)&Whh1, (void*)&bih1, (void*)&bhh1,
                     (void*)&Wih2, (void*)&Whh2, (void*)&bih2, (void*)&bhh2,
                     (void*)&Wfc, (void*)&bfc, &out, &cnt, &nblk };

    hipError_t err = hipErrorOutOfMemory;
    if (ws_size >= needRebal) {
        const unsigned ldsRebal = (unsigned)(32 * K1LDS + 32 * KP) * 2u;  // 147456
        if (hipFuncSetAttribute((const void*)rnn_rebal8,
                                hipFuncAttributeMaxDynamicSharedMemorySize,
                                (int)ldsRebal) == hipSuccess) {
            err = hipLaunchCooperativeKernel((const void*)rnn_rebal8,
                                             dim3(256), dim3(512), args,
                                             ldsRebal, stream);
        }
    }
    if (err != hipSuccess) {
        (void)hipGetLastError();
        (void)hipFuncSetAttribute((const void*)rnn_fallback8,
                                  hipFuncAttributeMaxDynamicSharedMemorySize, 131072);
        (void)hipLaunchCooperativeKernel((const void*)rnn_fallback8,
                                         dim3(256), dim3(512), args,
                                         131072u, stream);
    }
}

// Round 9
// 4722.931 us; speedup vs baseline: 1.0299x; 1.0299x over previous
//
#include <hip/hip_runtime.h>
#include <math.h>

// stacked_rnn R15: R13 reverted (proven 3548us: rebalanced dataflow, fenced
// barrier, barrier-window x-overlap) + ONE change: CH=32 deep load batches.
// R14 post-mortem: fence removal + agent-atomic loads regressed 37% with
// FETCH unchanged -> h-streams in R13 are already mostly L2-served; fence
// stays. Remaining residual ~5us/epoch = load-latency exposure at batch
// boundaries (2x CH=16 per h-seg). R13's VGPR=120 leaves ~130 headroom under
// the 2-waves/SIMD budget (256) -> single CH=32 batch per h-seg (128 VGPRs
// pinned via the proven sched_barrier(0)) halves exposed latency edges.
// Engagement check: VGPR must rise to ~180-200.

typedef __bf16 bf16;
typedef __bf16 bf16x8 __attribute__((ext_vector_type(8)));
typedef float floatx4 __attribute__((ext_vector_type(4)));
typedef unsigned long long ull;

#define B_   128
#define T_   256
#define H_   1024
#define I_   150
#define KX_  160
#define C_   60
#define K1LDS 1280   // L0 W1 LDS row width in elems (x 160 + h1 1024 + pad)
#define KP    1024   // Wih2 / Whh2 LDS row width
#define K2LDS 2048   // fallback kernel layer-2 row width
#define NLINES 32    // zeroed counter lines (primary uses 0..15 + flag @16;
                     // fallback uses 0..7 + flag @8)
#define CSTRIDE 64   // uints between lines (256B)
#define FLAGLINE 16
#define NCOLS 32     // gate-cols per block tile
#define NHC  8       // h-cols per block (NCOLS/4)
#define NT   2       // N-tiles of 16

template<int N> struct IC { static constexpr int value = N; };

__device__ __forceinline__ float sigmoidf_(float x) { return 1.f / (1.f + expf(-x)); }

// ---------------- conversion / init kernel ----------------
__global__ __launch_bounds__(256)
void convert_all(const float* __restrict__ x,
                 const float* __restrict__ h1in, const float* __restrict__ h2in,
                 bf16* __restrict__ xb, bf16* __restrict__ h1b0, bf16* __restrict__ h2b0,
                 unsigned* __restrict__ cnt)
{
    const size_t nXB = (size_t)T_ * B_ * KX_;   // 5242880
    const size_t nHC = (size_t)B_ * H_;         // 131072
    size_t idx = (size_t)blockIdx.x * 256 + threadIdx.x;

    if (idx < nXB) {                            // x [B][T][150] -> xb [T][B][160]
        size_t t = idx / (B_ * KX_);
        size_t r = idx - t * (B_ * KX_);
        size_t b = r / KX_, k = r - b * KX_;
        xb[idx] = (k < I_) ? (bf16)x[(b * T_ + t) * I_ + k] : (bf16)0.f;
        return;
    }
    idx -= nXB;
    if (idx < nHC) { h1b0[idx] = (bf16)h1in[idx]; return; }
    idx -= nHC;
    if (idx < nHC) { h2b0[idx] = (bf16)h2in[idx]; return; }
    idx -= nHC;
    if (idx < NLINES * CSTRIDE) cnt[idx] = 0u;
}

// ================= R15 primary: 8-wave rebalanced persistent kernel =========
// 256 blocks = 2 layers x 128 slices. layer=(bid>>3)&1, slice=(bid&7)|((bid>>4)<<3).
// L0: LDS = W1 (32x1280) + Wih2 slice (32x1024) = 144KB. epoch e in [0,T_]:
//   acc preloaded with x(e) part (overlapped into barrier e-1); dual-seg h1(e)
//   -> gates1 + p(e); publish p; epilogue h1(e+1) [e<T_].
// L1: LDS = Whh2 slice (32x1024) = 64KB. epoch e in [2,T_+1]:
//   prefetch p(e-1) regs; stream h2(e-2); acc += p; epilogue h2(e-1).
__global__ __launch_bounds__(512, 2)
void rnn_rebal8(const bf16* __restrict__ xb,
                bf16* __restrict__ h1b0, bf16* __restrict__ h1b1,
                bf16* __restrict__ h2b0, bf16* __restrict__ h2b1,
                float* __restrict__ p0, float* __restrict__ p1,
                const float* __restrict__ c1in, const float* __restrict__ c2in,
                const float* __restrict__ Wih1, const float* __restrict__ Whh1,
                const float* __restrict__ bih1, const float* __restrict__ bhh1,
                const float* __restrict__ Wih2, const float* __restrict__ Whh2,
                const float* __restrict__ bih2, const float* __restrict__ bhh2,
                const float* __restrict__ Wfc, const float* __restrict__ bfc,
                float* __restrict__ out, unsigned* __restrict__ cnt, int nblk)
{
    extern __shared__ bf16 lds[];
    __shared__ __align__(16) bf16 hst[8][16][NHC];   // epilogue staging

    const int tid   = threadIdx.x;
    const int bid   = blockIdx.x;
    const int layer = (bid >> 3) & 1;
    const int slice = (bid & 7) | ((bid >> 4) << 3);
    const int n0h   = slice * NHC;
    const int arr_per_line = nblk >> 4;          // 16 lines x 16 blocks
    bf16* ldsP = lds + 32 * K1LDS;               // L0's Wih2 region

    // ---- stage weights fp32->bf16 into swizzled LDS (once) ----
    if (layer == 0) {
        {   // W1 region: 32 rows x K1LDS (x [0,160), h1 [160,1184), pad)
            const int cpr = K1LDS >> 3;           // 160
            const int total = NCOLS * cpr;
            for (int ci = tid; ci < total; ci += 512) {
                int r = ci / cpr, c = ci - r * cpr;
                int g = r / NHC, j = r - g * NHC;
                int grow = (g << 10) + n0h + j;
                int k0 = c << 3;
                float v[8];
#pragma unroll
                for (int u = 0; u < 8; ++u) {
                    int k = k0 + u;
                    v[u] = (k < I_) ? Wih1[(size_t)grow * I_ + k]
                         : (k < KX_) ? 0.f
                         : (k < KX_ + H_) ? Whh1[(size_t)grow * H_ + (k - KX_)] : 0.f;
                }
                int cs = (c & ~15) | ((c ^ r) & 15);
                bf16* dst = lds + (size_t)r * K1LDS + (cs << 3);
#pragma unroll
                for (int u = 0; u < 8; ++u) dst[u] = (bf16)v[u];
            }
        }
        {   // Wih2 region: 32 rows x KP
            const int cpr = KP >> 3;              // 128
            const int total = NCOLS * cpr;
            for (int ci = tid; ci < total; ci += 512) {
                int r = ci / cpr, c = ci - r * cpr;
                int g = r / NHC, j = r - g * NHC;
                int grow = (g << 10) + n0h + j;
                int k0 = c << 3;
                float v[8];
#pragma unroll
                for (int u = 0; u < 8; ++u) v[u] = Wih2[(size_t)grow * H_ + k0 + u];
                int cs = (c & ~15) | ((c ^ r) & 15);
                bf16* dst = ldsP + (size_t)r * KP + (cs << 3);
#pragma unroll
                for (int u = 0; u < 8; ++u) dst[u] = (bf16)v[u];
            }
        }
    } else {
        // Whh2 region: 32 rows x KP
        const int cpr = KP >> 3;
        const int total = NCOLS * cpr;
        for (int ci = tid; ci < total; ci += 512) {
            int r = ci / cpr, c = ci - r * cpr;
            int g = r / NHC, j = r - g * NHC;
            int grow = (g << 10) + n0h + j;
            int k0 = c << 3;
            float v[8];
#pragma unroll
            for (int u = 0; u < 8; ++u) v[u] = Whh2[(size_t)grow * H_ + k0 + u];
            int cs = (c & ~15) | ((c ^ r) & 15);
            bf16* dst = lds + (size_t)r * KP + (cs << 3);
#pragma unroll
            for (int u = 0; u < 8; ++u) dst[u] = (bf16)v[u];
        }
    }
    __syncthreads();

    const int lane = tid & 63;
    const int wv   = tid >> 6;          // 0..7
    const int jj   = lane & (NHC - 1);
    const int quad = lane >> 4;

    float4 bias;
    {
        const float* bi = layer ? bih2 : bih1;
        const float* bh = layer ? bhh2 : bhh1;
        int col = n0h + jj;
        bias.x = bi[col] + bh[col];
        bias.y = bi[col + H_] + bh[col + H_];
        bias.z = bi[col + 2 * H_] + bh[col + 2 * H_];
        bias.w = bi[col + 3 * H_] + bh[col + 3 * H_];
    }

    float creg[2];
    {
        const float* cin = layer ? c2in : c1in;
        int dup = (lane >> 3) & 1;
#pragma unroll
        for (int rp = 0; rp < 2; ++rp) {
            int row = wv * 16 + quad * 4 + rp * 2 + dup;
            creg[rp] = cin[(size_t)row * H_ + n0h + jj];
        }
    }

    floatx4 acc[NT];
    floatx4 pacc[NT];

    // generic single-target K-segment; CH up to 32 loads pinned in one batch
    auto seg1 = [&](const bf16* A, int ldA, const bf16* Bb, int ldB,
                    auto nksC, int ksBase) {
        constexpr int NKS = decltype(nksC)::value;
        constexpr int CH  = NKS < 32 ? NKS : 32;
        const int arow = wv * 16 + (lane & 15);
        const bf16* a0 = A + (size_t)arow * ldA + quad * 8;
        for (int blk = 0; blk < NKS; blk += CH) {
            bf16x8 a0r[CH];
#pragma unroll
            for (int i = 0; i < CH; ++i)
                a0r[i] = *(const bf16x8*)(a0 + (blk + i) * 32);
            __builtin_amdgcn_sched_barrier(0);   // pin the batch (sched-only)
#pragma unroll
            for (int i = 0; i < CH; ++i) {
                int c = (ksBase + blk + i) * 4 + quad;
#pragma unroll
                for (int t = 0; t < NT; ++t) {
                    int r = t * 16 + (lane & 15);
                    int cs = (c & ~15) | ((c ^ r) & 15);
                    bf16x8 bfr = *(const bf16x8*)(Bb + (size_t)r * ldB + (cs << 3));
                    acc[t] = __builtin_amdgcn_mfma_f32_16x16x32_bf16(a0r[i], bfr, acc[t], 0, 0, 0);
                }
            }
        }
    };

    // dual-target h1-segment (L0): one CH=32 batch; gates1 into acc (W1,
    // ksBase 5) AND p into pacc (Wih2, ksBase 0) from the SAME A stream.
    auto segDual = [&](const bf16* A) {
        const int arow = wv * 16 + (lane & 15);
        const bf16* a0 = A + (size_t)arow * H_ + quad * 8;
        bf16x8 a0r[32];
#pragma unroll
        for (int i = 0; i < 32; ++i)
            a0r[i] = *(const bf16x8*)(a0 + i * 32);
        __builtin_amdgcn_sched_barrier(0);       // pin the batch (sched-only)
#pragma unroll
        for (int i = 0; i < 32; ++i) {
            int c1 = (5 + i) * 4 + quad;
            int cp = i * 4 + quad;
#pragma unroll
            for (int t = 0; t < NT; ++t) {
                int r = t * 16 + (lane & 15);
                int cs1 = (c1 & ~15) | ((c1 ^ r) & 15);
                bf16x8 b1 = *(const bf16x8*)(lds + (size_t)r * K1LDS + (cs1 << 3));
                acc[t] = __builtin_amdgcn_mfma_f32_16x16x32_bf16(a0r[i], b1, acc[t], 0, 0, 0);
                int csp = (cp & ~15) | ((cp ^ r) & 15);
                bf16x8 bp = *(const bf16x8*)(ldsP + (size_t)r * KP + (csp << 3));
                pacc[t] = __builtin_amdgcn_mfma_f32_16x16x32_bf16(a0r[i], bp, pacc[t], 0, 0, 0);
            }
        }
    };

    // epilogue: shfl-gather gates, update creg, stage h to LDS, store h
    auto epilogue = [&](bf16* hw) {
        const int base = lane & 48;
#pragma unroll
        for (int r = 0; r < 4; ++r) {
            float vi = __shfl(acc[0][r], base + jj, 64);
            float vf = __shfl(acc[0][r], base + 8 + jj, 64);
            float vg = __shfl(acc[1][r], base + jj, 64);
            float vo = __shfl(acc[1][r], base + 8 + jj, 64);
            bool cond = (((lane >> 3) & 1) == (r & 1));
            int slot = r >> 1;
            if (cond) {
                float cv = creg[slot];
                float cn = sigmoidf_(vf + bias.y) * cv
                         + sigmoidf_(vi + bias.x) * tanhf(vg + bias.z);
                creg[slot] = cn;
                float hn = sigmoidf_(vo + bias.w) * tanhf(cn);
                hst[wv][quad * 4 + r][jj] = (bf16)hn;
            }
        }
        __syncthreads();
        if (lane < 32) {
            int row_l = lane >> 1, cg = lane & 1;
            ull v = *(const ull*)&hst[wv][row_l][cg * 4];
            __hip_atomic_store((ull*)(hw + (size_t)(wv * 16 + row_l) * H_ + n0h + cg * 4),
                               v, __ATOMIC_RELAXED, __HIP_MEMORY_SCOPE_AGENT);
        }
    };

    // prologue (L0): zero accs and pre-compute x(0) contribution
    if (layer == 0) {
#pragma unroll
        for (int t = 0; t < NT; ++t) {
            acc[t]  = (floatx4){0.f, 0.f, 0.f, 0.f};
            pacc[t] = (floatx4){0.f, 0.f, 0.f, 0.f};
        }
        seg1(xb, KX_, lds, K1LDS, IC<5>{}, 0);     // x(0)
    }

    for (int e = 0; e <= T_ + 1; ++e) {
        if (layer == 0 && e <= T_) {
            // acc holds x(e) part (preloaded); dual-seg adds h1(e) part + p(e)
            const bf16* h1r = (e & 1) ? h1b1 : h1b0;          // h1^(e)
            segDual(h1r);

            // publish p(e) slice (f32, relaxed-agent write-through)
            float* pw = ((e & 1) ? p1 : p0) + (size_t)slice * B_ * NCOLS;
#pragma unroll
            for (int t = 0; t < NT; ++t)
#pragma unroll
                for (int r = 0; r < 4; ++r) {
                    int row = wv * 16 + quad * 4 + r;
                    __hip_atomic_store(pw + (size_t)row * NCOLS + t * 16 + (lane & 15),
                                       pacc[t][r], __ATOMIC_RELAXED, __HIP_MEMORY_SCOPE_AGENT);
                }

            if (e < T_) {
                bf16* hw = (e & 1) ? h1b0 : h1b1;              // h1^(e+1)
                epilogue(hw);
            }
        } else if (layer == 1 && e >= 2) {
#pragma unroll
            for (int t = 0; t < NT; ++t) acc[t] = (floatx4){0.f, 0.f, 0.f, 0.f};

            // prefetch p(e-1) slice into registers (post-fence: coherent)
            const float* pr = ((e & 1) ? p0 : p1) + (size_t)slice * B_ * NCOLS;
            float pv[NT][4];
#pragma unroll
            for (int t = 0; t < NT; ++t)
#pragma unroll
                for (int r = 0; r < 4; ++r) {
                    int row = wv * 16 + quad * 4 + r;
                    pv[t][r] = pr[(size_t)row * NCOLS + t * 16 + (lane & 15)];
                }

            const bf16* h2r = (e & 1) ? h2b1 : h2b0;           // h2^(e-2)
            seg1(h2r, H_, lds, KP, IC<32>{}, 0);

#pragma unroll
            for (int t = 0; t < NT; ++t)
#pragma unroll
                for (int r = 0; r < 4; ++r) acc[t][r] += pv[t][r];

            bf16* hw = (e & 1) ? h2b0 : h2b1;                  // h2^(e-1)
            epilogue(hw);
        }

        // ---- barrier: arrive -> overlapped x-prefetch (L0) -> detect -> fence
        asm volatile("s_waitcnt vmcnt(0)" ::: "memory");
        __syncthreads();
        const unsigned etag = (unsigned)(e + 1);
        if (tid == 0)
            __hip_atomic_fetch_add(cnt + (bid & 15) * CSTRIDE, 1u,
                                   __ATOMIC_RELAXED, __HIP_MEMORY_SCOPE_AGENT);
        // overlapped work in the barrier window: next-epoch x-seg on
        // immutable input (register results survive the fence)
        if (layer == 0 && e < T_) {
#pragma unroll
            for (int t = 0; t < NT; ++t) {
                acc[t]  = (floatx4){0.f, 0.f, 0.f, 0.f};
                pacc[t] = (floatx4){0.f, 0.f, 0.f, 0.f};
            }
            if (e + 1 < T_)
                seg1(xb + (size_t)(e + 1) * B_ * KX_, KX_, lds, K1LDS, IC<5>{}, 0);
        }
        if (bid == 0) {
            if (tid < 16) {
                const unsigned tgt = etag * (unsigned)arr_per_line;
                const unsigned* cp = cnt + tid * CSTRIDE;
                while (__hip_atomic_load(cp, __ATOMIC_RELAXED, __HIP_MEMORY_SCOPE_AGENT) < tgt)
                    __builtin_amdgcn_s_sleep(1);
            }
            if (tid == 0)
                __hip_atomic_store(cnt + FLAGLINE * CSTRIDE, etag,
                                   __ATOMIC_RELAXED, __HIP_MEMORY_SCOPE_AGENT);
        } else {
            if (tid == 0) {
                const unsigned* fp = cnt + FLAGLINE * CSTRIDE;
                while (__hip_atomic_load(fp, __ATOMIC_RELAXED, __HIP_MEMORY_SCOPE_AGENT) < etag)
                    __builtin_amdgcn_s_sleep(1);
            }
        }
        __syncthreads();
        // acquire (cache inv) by wave 0 only
        if (tid < 64)
            __builtin_amdgcn_fence(__ATOMIC_ACQUIRE, "agent");
        __syncthreads();
    }

    // ---- fused FC: out = h2^(256) @ Wfc^T + bfc ; h2^(256) is in h2b0 ----
    if (bid < B_) {
        const bf16* h2f = h2b0;
        for (int c = wv; c < C_; c += 8) {
            float a = 0.f;
            for (int k = lane; k < H_; k += 64)
                a += (float)h2f[(size_t)bid * H_ + k] * Wfc[(size_t)c * H_ + k];
#pragma unroll
            for (int off = 32; off; off >>= 1) a += __shfl_down(a, off, 64);
            if (lane == 0) out[bid * C_ + c] = a + bfc[c];
        }
    }
}

// ============ fallback: PROVEN R10 8-wave kernel (5140us, passed) ===========
// Same signature as primary; p0/p1 unused. Original R6 dataflow, fence-based.
__global__ __launch_bounds__(512, 2)
void rnn_fallback8(const bf16* __restrict__ xb,
                   bf16* __restrict__ h1b0, bf16* __restrict__ h1b1,
                   bf16* __restrict__ h2b0, bf16* __restrict__ h2b1,
                   float* __restrict__ p0, float* __restrict__ p1,
                   const float* __restrict__ c1in, const float* __restrict__ c2in,
                   const float* __restrict__ Wih1, const float* __restrict__ Whh1,
                   const float* __restrict__ bih1, const float* __restrict__ bhh1,
                   const float* __restrict__ Wih2, const float* __restrict__ Whh2,
                   const float* __restrict__ bih2, const float* __restrict__ bhh2,
                   const float* __restrict__ Wfc, const float* __restrict__ bfc,
                   float* __restrict__ out, unsigned* __restrict__ cnt, int nblk)
{
    extern __shared__ bf16 lds[];
    __shared__ __align__(16) bf16 hst[8][16][NHC];

    const int tid   = threadIdx.x;
    const int bid   = blockIdx.x;
    const int layer = (bid >> 3) & 1;
    const int slice = (bid & 7) | ((bid >> 4) << 3);
    const int n0h   = slice * NHC;
    const int KLDS  = layer ? K2LDS : K1LDS;
    const int arr_per_line = nblk >> 3;

    {   // stage weights (R6 combined map)
        const int cpr = KLDS >> 3;
        const int total = NCOLS * cpr;
        for (int ci = tid; ci < total; ci += 512) {
            int r = ci / cpr, c = ci - r * cpr;
            int g = r / NHC, j = r - g * NHC;
            int grow = (g << 10) + n0h + j;
            int k0 = c << 3;
            float v[8];
#pragma unroll
            for (int u = 0; u < 8; ++u) {
                int k = k0 + u;
                if (layer == 0)
                    v[u] = (k < I_) ? Wih1[(size_t)grow * I_ + k]
                         : (k < KX_) ? 0.f
                         : (k < KX_ + H_) ? Whh1[(size_t)grow * H_ + (k - KX_)] : 0.f;
                else
                    v[u] = (k < H_) ? Wih2[(size_t)grow * H_ + k]
                                    : Whh2[(size_t)grow * H_ + (k - H_)];
            }
            int cs = (c & ~15) | ((c ^ r) & 15);
            bf16* dst = lds + (size_t)r * KLDS + (cs << 3);
#pragma unroll
            for (int u = 0; u < 8; ++u) dst[u] = (bf16)v[u];
        }
    }
    __syncthreads();

    const int lane = tid & 63;
    const int wv   = tid >> 6;
    const int jj   = lane & (NHC - 1);
    const int quad = lane >> 4;

    float4 bias;
    {
        const float* bi = layer ? bih2 : bih1;
        const float* bh = layer ? bhh2 : bhh1;
        int col = n0h + jj;
        bias.x = bi[col] + bh[col];
        bias.y = bi[col + H_] + bh[col + H_];
        bias.z = bi[col + 2 * H_] + bh[col + 2 * H_];
        bias.w = bi[col + 3 * H_] + bh[col + 3 * H_];
    }

    float creg[2];
    {
        const float* cin = layer ? c2in : c1in;
        int dup = (lane >> 3) & 1;
#pragma unroll
        for (int rp = 0; rp < 2; ++rp) {
            int row = wv * 16 + quad * 4 + rp * 2 + dup;
            creg[rp] = cin[(size_t)row * H_ + n0h + jj];
        }
    }

    floatx4 acc[NT];

    auto seg = [&](const bf16* A, int ldA, auto nksC, int ksBase) {
        constexpr int NKS = decltype(nksC)::value;
        constexpr int CH  = NKS < 16 ? NKS : 16;
        const int arow = wv * 16 + (lane & 15);
        const bf16* a0 = A + (size_t)arow * ldA + quad * 8;
        for (int blk = 0; blk < NKS; blk += CH) {
            bf16x8 a0r[CH];
#pragma unroll
            for (int i = 0; i < CH; ++i)
                a0r[i] = *(const bf16x8*)(a0 + (blk + i) * 32);
            __builtin_amdgcn_sched_barrier(0);
#pragma unroll
            for (int i = 0; i < CH; ++i) {
                int c = (ksBase + blk + i) * 4 + quad;
#pragma unroll
                for (int t = 0; t < NT; ++t) {
                    int r = t * 16 + (lane & 15);
                    int cs = (c & ~15) | ((c ^ r) & 15);
                    bf16x8 bfr = *(const bf16x8*)(lds + (size_t)r * KLDS + (cs << 3));
                    acc[t] = __builtin_amdgcn_mfma_f32_16x16x32_bf16(a0r[i], bfr, acc[t], 0, 0, 0);
                }
            }
        }
    };

    for (int e = 0; e <= T_; ++e) {
        const bool active = layer == 0 ? (e < T_) : (e >= 1);
        if (active) {
#pragma unroll
            for (int t = 0; t < NT; ++t) acc[t] = (floatx4){0.f, 0.f, 0.f, 0.f};

            const bf16* h1r = (e & 1) ? h1b1 : h1b0;
            if (layer == 0) {
                const bf16* xt = xb + (size_t)e * B_ * KX_;
                seg(xt, KX_, IC<5>{}, 0);
                seg(h1r, H_, IC<32>{}, 5);
            } else {
                const bf16* h2r = (e & 1) ? h2b0 : h2b1;
                seg(h1r, H_, IC<32>{}, 0);
                seg(h2r, H_, IC<32>{}, 32);
            }
            bf16* hw = (layer == 0) ? ((e & 1) ? h1b0 : h1b1)
                                    : ((e & 1) ? h2b1 : h2b0);

            const int base = lane & 48;
#pragma unroll
            for (int r = 0; r < 4; ++r) {
                float vi = __shfl(acc[0][r], base + jj, 64);
                float vf = __shfl(acc[0][r], base + 8 + jj, 64);
                float vg = __shfl(acc[1][r], base + jj, 64);
                float vo = __shfl(acc[1][r], base + 8 + jj, 64);
                bool cond = (((lane >> 3) & 1) == (r & 1));
                int slot = r >> 1;
                if (cond) {
                    float cv = creg[slot];
                    float cn = sigmoidf_(vf + bias.y) * cv
                             + sigmoidf_(vi + bias.x) * tanhf(vg + bias.z);
                    creg[slot] = cn;
                    float hn = sigmoidf_(vo + bias.w) * tanhf(cn);
                    hst[wv][quad * 4 + r][jj] = (bf16)hn;
                }
            }
            __syncthreads();
            if (lane < 32) {
                int row_l = lane >> 1, cg = lane & 1;
                ull v = *(const ull*)&hst[wv][row_l][cg * 4];
                __hip_atomic_store((ull*)(hw + (size_t)(wv * 16 + row_l) * H_ + n0h + cg * 4),
                                   v, __ATOMIC_RELAXED, __HIP_MEMORY_SCOPE_AGENT);
            }
        }

        asm volatile("s_waitcnt vmcnt(0)" ::: "memory");
        __syncthreads();
        const unsigned etag = (unsigned)(e + 1);
        if (bid == 0) {
            if (tid == 0)
                __hip_atomic_fetch_add(cnt, 1u, __ATOMIC_RELAXED, __HIP_MEMORY_SCOPE_AGENT);
            if (tid < 8) {
                const unsigned tgt = etag * (unsigned)arr_per_line;
                const unsigned* cp = cnt + tid * CSTRIDE;
                while (__hip_atomic_load(cp, __ATOMIC_RELAXED, __HIP_MEMORY_SCOPE_AGENT) < tgt)
                    __builtin_amdgcn_s_sleep(1);
            }
            if (tid == 0)
                __hip_atomic_store(cnt + 8 * CSTRIDE, etag,
                                   __ATOMIC_RELAXED, __HIP_MEMORY_SCOPE_AGENT);
        } else {
            if (tid == 0) {
                __hip_atomic_fetch_add(cnt + (bid & 7) * CSTRIDE, 1u,
                                       __ATOMIC_RELAXED, __HIP_MEMORY_SCOPE_AGENT);
                const unsigned* fp = cnt + 8 * CSTRIDE;
                while (__hip_atomic_load(fp, __ATOMIC_RELAXED, __HIP_MEMORY_SCOPE_AGENT) < etag)
                    __builtin_amdgcn_s_sleep(1);
            }
        }
        __syncthreads();
        if (tid < 64)
            __builtin_amdgcn_fence(__ATOMIC_ACQUIRE, "agent");
        __syncthreads();
    }

    if (bid < B_) {
        const bf16* h2f = h2b0;
        for (int c = wv; c < C_; c += 8) {
            float a = 0.f;
            for (int k = lane; k < H_; k += 64)
                a += (float)h2f[(size_t)bid * H_ + k] * Wfc[(size_t)c * H_ + k];
#pragma unroll
            for (int off = 32; off; off >>= 1) a += __shfl_down(a, off, 64);
            if (lane == 0) out[bid * C_ + c] = a + bfc[c];
        }
    }
}

extern "C" void kernel_launch(void* const* d_in, const int* in_sizes, int n_in,
                              void* d_out, int out_size, void* d_ws, size_t ws_size,
                              hipStream_t stream)
{
    const float* x    = (const float*)d_in[0];
    const float* h1in = (const float*)d_in[1];
    const float* c1in = (const float*)d_in[2];
    const float* h2in = (const float*)d_in[3];
    const float* c2in = (const float*)d_in[4];
    const float* Wih1 = (const float*)d_in[5];
    const float* Whh1 = (const float*)d_in[6];
    const float* bih1 = (const float*)d_in[7];
    const float* bhh1 = (const float*)d_in[8];
    const float* Wih2 = (const float*)d_in[9];
    const float* Whh2 = (const float*)d_in[10];
    const float* bih2 = (const float*)d_in[11];
    const float* bhh2 = (const float*)d_in[12];
    const float* Wfc  = (const float*)d_in[13];
    const float* bfc  = (const float*)d_in[14];
    float* out = (float*)d_out;

    // ws carve: base ~11.5MB always; p buffers (+4MB) only if ws fits
    const size_t szXB  = (size_t)T_ * B_ * KX_ * 2;        // 10485760
    const size_t szH   = (size_t)B_ * H_ * 2;              // 262144
    const size_t szCnt = (size_t)NLINES * CSTRIDE * 4;     // 8192
    const size_t szP   = (size_t)128 * B_ * NCOLS * 4;     // 2097152
    const size_t needBase  = szXB + 4 * szH + szCnt;
    const size_t needRebal = needBase + 2 * szP;

    char* p = (char*)d_ws;
    bf16* xb = (bf16*)p;    p += szXB;
    bf16* h1b0 = (bf16*)p;  p += szH;
    bf16* h1b1 = (bf16*)p;  p += szH;
    bf16* h2b0 = (bf16*)p;  p += szH;
    bf16* h2b1 = (bf16*)p;  p += szH;
    unsigned* cnt = (unsigned*)p;  p += szCnt;
    float* p0 = (float*)p;  p += szP;
    float* p1 = (float*)p;

    const size_t citems = (size_t)T_ * B_ * KX_ + 2 * (size_t)B_ * H_ + NLINES * CSTRIDE;
    convert_all<<<(int)((citems + 255) / 256), 256, 0, stream>>>(
        x, h1in, h2in, xb, h1b0, h2b0, cnt);

    int nblk = 256;
    void* args[] = { &xb, &h1b0, &h1b1, &h2b0, &h2b1, &p0, &p1,
                     (void*)&c1in, (void*)&c2in,
                     (void*)&Wih1, (void*)&Whh1, (void*)&bih1, (void*)&bhh1,
                     (void*)&Wih2, (void*)&Whh2, (void*)&bih2, (void*)&bhh2,
                     (void*)&Wfc, (void*)&bfc, &out, &cnt, &nblk };

    hipError_t err = hipErrorOutOfMemory;
    if (ws_size >= needRebal) {
        const unsigned ldsRebal = (unsigned)(32 * K1LDS + 32 * KP) * 2u;  // 147456
        if (hipFuncSetAttribute((const void*)rnn_rebal8,
                                hipFuncAttributeMaxDynamicSharedMemorySize,
                                (int)ldsRebal) == hipSuccess) {
            err = hipLaunchCooperativeKernel((const void*)rnn_rebal8,
                                             dim3(256), dim3(512), args,
                                             ldsRebal, stream);
        }
    }
    if (err != hipSuccess) {
        (void)hipGetLastError();
        (void)hipFuncSetAttribute((const void*)rnn_fallback8,
                                  hipFuncAttributeMaxDynamicSharedMemorySize, 131072);
        (void)hipLaunchCooperativeKernel((const void*)rnn_fallback8,
                                         dim3(256), dim3(512), args,
                                         131072u, stream);
    }
}

// Round 10
// 3329.784 us; speedup vs baseline: 1.4609x; 1.4184x over previous
//
#include <hip/hip_runtime.h>
#include <math.h>

// stacked_rnn R16: decoupled per-layer barriers + triple-buffered p.
// R15 post-mortem: CH=32 spilled (VGPR stuck 128, WRITE +135MB scratch) ->
// ILP lever dead; reverted to R13 segs (CH=16). R16's change: split the
// global barrier into two group barriers. Dep graph: L0 reads only L0 output
// (h1); L1 reads L1 output (h2) + L0's p with 1-epoch lag. With p triple-
// buffered, L0 needs only flagL1 >= etag-2 (slack 2) -> L0 free-runs ahead;
// L1's wait on flagL0 is pre-satisfied. Each group's barrier: 128 arrivals
// over 16 lines (8 RMWs/line), own flag. Per-epoch fence retained (R14
// lesson). Final join before FC. Fallback = R13 VERBATIM (3548us proven),
// so ws/LDS failure costs nothing.

typedef __bf16 bf16;
typedef __bf16 bf16x8 __attribute__((ext_vector_type(8)));
typedef float floatx4 __attribute__((ext_vector_type(4)));
typedef unsigned long long ull;

#define B_   128
#define T_   256
#define H_   1024
#define I_   150
#define KX_  160
#define C_   60
#define K1LDS 1280   // L0 W1 LDS row width in elems (x 160 + h1 1024 + pad)
#define KP    1024   // Wih2 / Whh2 LDS row width
#define NLINES 40    // zeroed counter lines (primary: 0..31 arrivals, 32/33 flags;
                     // fallback: 0..15 arrivals + flag @16)
#define CSTRIDE 64   // uints between lines (256B)
#define FLAGLINE 16  // fallback's flag line
#define L0FLAG 32    // primary: L0 group flag line
#define L1FLAG 33    // primary: L1 group flag line
#define NCOLS 32     // gate-cols per block tile
#define NHC  8       // h-cols per block (NCOLS/4)
#define NT   2       // N-tiles of 16

template<int N> struct IC { static constexpr int value = N; };

__device__ __forceinline__ float sigmoidf_(float x) { return 1.f / (1.f + expf(-x)); }

// ---------------- conversion / init kernel ----------------
__global__ __launch_bounds__(256)
void convert_all(const float* __restrict__ x,
                 const float* __restrict__ h1in, const float* __restrict__ h2in,
                 bf16* __restrict__ xb, bf16* __restrict__ h1b0, bf16* __restrict__ h2b0,
                 unsigned* __restrict__ cnt)
{
    const size_t nXB = (size_t)T_ * B_ * KX_;   // 5242880
    const size_t nHC = (size_t)B_ * H_;         // 131072
    size_t idx = (size_t)blockIdx.x * 256 + threadIdx.x;

    if (idx < nXB) {                            // x [B][T][150] -> xb [T][B][160]
        size_t t = idx / (B_ * KX_);
        size_t r = idx - t * (B_ * KX_);
        size_t b = r / KX_, k = r - b * KX_;
        xb[idx] = (k < I_) ? (bf16)x[(b * T_ + t) * I_ + k] : (bf16)0.f;
        return;
    }
    idx -= nXB;
    if (idx < nHC) { h1b0[idx] = (bf16)h1in[idx]; return; }
    idx -= nHC;
    if (idx < nHC) { h2b0[idx] = (bf16)h2in[idx]; return; }
    idx -= nHC;
    if (idx < NLINES * CSTRIDE) cnt[idx] = 0u;
}

// ---- shared staging helper (both persistent kernels, 512 threads) ----
__device__ __forceinline__ void stage_rebal(
    bf16* lds, bf16* ldsP, int tid, int layer, int n0h,
    const float* Wih1, const float* Whh1, const float* Wih2, const float* Whh2)
{
    if (layer == 0) {
        {   // W1 region: 32 rows x K1LDS (x [0,160), h1 [160,1184), pad)
            const int cpr = K1LDS >> 3;           // 160
            const int total = NCOLS * cpr;
            for (int ci = tid; ci < total; ci += 512) {
                int r = ci / cpr, c = ci - r * cpr;
                int g = r / NHC, j = r - g * NHC;
                int grow = (g << 10) + n0h + j;
                int k0 = c << 3;
                float v[8];
#pragma unroll
                for (int u = 0; u < 8; ++u) {
                    int k = k0 + u;
                    v[u] = (k < I_) ? Wih1[(size_t)grow * I_ + k]
                         : (k < KX_) ? 0.f
                         : (k < KX_ + H_) ? Whh1[(size_t)grow * H_ + (k - KX_)] : 0.f;
                }
                int cs = (c & ~15) | ((c ^ r) & 15);
                bf16* dst = lds + (size_t)r * K1LDS + (cs << 3);
#pragma unroll
                for (int u = 0; u < 8; ++u) dst[u] = (bf16)v[u];
            }
        }
        {   // Wih2 region: 32 rows x KP
            const int cpr = KP >> 3;              // 128
            const int total = NCOLS * cpr;
            for (int ci = tid; ci < total; ci += 512) {
                int r = ci / cpr, c = ci - r * cpr;
                int g = r / NHC, j = r - g * NHC;
                int grow = (g << 10) + n0h + j;
                int k0 = c << 3;
                float v[8];
#pragma unroll
                for (int u = 0; u < 8; ++u) v[u] = Wih2[(size_t)grow * H_ + k0 + u];
                int cs = (c & ~15) | ((c ^ r) & 15);
                bf16* dst = ldsP + (size_t)r * KP + (cs << 3);
#pragma unroll
                for (int u = 0; u < 8; ++u) dst[u] = (bf16)v[u];
            }
        }
    } else {
        // Whh2 region: 32 rows x KP
        const int cpr = KP >> 3;
        const int total = NCOLS * cpr;
        for (int ci = tid; ci < total; ci += 512) {
            int r = ci / cpr, c = ci - r * cpr;
            int g = r / NHC, j = r - g * NHC;
            int grow = (g << 10) + n0h + j;
            int k0 = c << 3;
            float v[8];
#pragma unroll
            for (int u = 0; u < 8; ++u) v[u] = Whh2[(size_t)grow * H_ + k0 + u];
            int cs = (c & ~15) | ((c ^ r) & 15);
            bf16* dst = lds + (size_t)r * KP + (cs << 3);
#pragma unroll
            for (int u = 0; u < 8; ++u) dst[u] = (bf16)v[u];
        }
    }
}

// ================= R16 primary: decoupled-barrier rebalanced kernel =========
// 256 blocks = 2 layers x 128 slices. layer=(bid>>3)&1, slice=(bid&7)|((bid>>4)<<3).
// Arrival line: group*16 + ((bid&7) | (((bid>>4)&1)<<3)) -> 8 blocks/line.
// flagL0@32, flagL1@33. L0 waits {flagL0>=etag, flagL1>=etag-2}; L1 waits
// {flagL1>=etag, flagL0>=etag}. p triple-buffered: write p[e%3], read p[(e+2)%3].
__global__ __launch_bounds__(512, 2)
void rnn_decoup8(const bf16* __restrict__ xb,
                 bf16* __restrict__ h1b0, bf16* __restrict__ h1b1,
                 bf16* __restrict__ h2b0, bf16* __restrict__ h2b1,
                 float* __restrict__ p0, float* __restrict__ p1, float* __restrict__ p2,
                 const float* __restrict__ c1in, const float* __restrict__ c2in,
                 const float* __restrict__ Wih1, const float* __restrict__ Whh1,
                 const float* __restrict__ bih1, const float* __restrict__ bhh1,
                 const float* __restrict__ Wih2, const float* __restrict__ Whh2,
                 const float* __restrict__ bih2, const float* __restrict__ bhh2,
                 const float* __restrict__ Wfc, const float* __restrict__ bfc,
                 float* __restrict__ out, unsigned* __restrict__ cnt, int nblk)
{
    extern __shared__ bf16 lds[];
    __shared__ __align__(16) bf16 hst[8][16][NHC];   // epilogue staging

    const int tid   = threadIdx.x;
    const int bid   = blockIdx.x;
    const int layer = (bid >> 3) & 1;
    const int slice = (bid & 7) | ((bid >> 4) << 3);
    const int n0h   = slice * NHC;
    const int line  = layer * 16 + ((bid & 7) | (((bid >> 4) & 1) << 3));
    bf16* ldsP = lds + 32 * K1LDS;               // L0's Wih2 region

    stage_rebal(lds, ldsP, tid, layer, n0h, Wih1, Whh1, Wih2, Whh2);
    __syncthreads();

    const int lane = tid & 63;
    const int wv   = tid >> 6;          // 0..7
    const int jj   = lane & (NHC - 1);
    const int quad = lane >> 4;

    float4 bias;
    {
        const float* bi = layer ? bih2 : bih1;
        const float* bh = layer ? bhh2 : bhh1;
        int col = n0h + jj;
        bias.x = bi[col] + bh[col];
        bias.y = bi[col + H_] + bh[col + H_];
        bias.z = bi[col + 2 * H_] + bh[col + 2 * H_];
        bias.w = bi[col + 3 * H_] + bh[col + 3 * H_];
    }

    float creg[2];
    {
        const float* cin = layer ? c2in : c1in;
        int dup = (lane >> 3) & 1;
#pragma unroll
        for (int rp = 0; rp < 2; ++rp) {
            int row = wv * 16 + quad * 4 + rp * 2 + dup;
            creg[rp] = cin[(size_t)row * H_ + n0h + jj];
        }
    }

    floatx4 acc[NT];
    floatx4 pacc[NT];

    // generic single-target K-segment (CH=16, proven)
    auto seg1 = [&](const bf16* A, int ldA, const bf16* Bb, int ldB,
                    auto nksC, int ksBase) {
        constexpr int NKS = decltype(nksC)::value;
        constexpr int CH  = NKS < 16 ? NKS : 16;
        const int arow = wv * 16 + (lane & 15);
        const bf16* a0 = A + (size_t)arow * ldA + quad * 8;
        for (int blk = 0; blk < NKS; blk += CH) {
            bf16x8 a0r[CH];
#pragma unroll
            for (int i = 0; i < CH; ++i)
                a0r[i] = *(const bf16x8*)(a0 + (blk + i) * 32);
            __builtin_amdgcn_sched_barrier(0);
#pragma unroll
            for (int i = 0; i < CH; ++i) {
                int c = (ksBase + blk + i) * 4 + quad;
#pragma unroll
                for (int t = 0; t < NT; ++t) {
                    int r = t * 16 + (lane & 15);
                    int cs = (c & ~15) | ((c ^ r) & 15);
                    bf16x8 bfr = *(const bf16x8*)(Bb + (size_t)r * ldB + (cs << 3));
                    acc[t] = __builtin_amdgcn_mfma_f32_16x16x32_bf16(a0r[i], bfr, acc[t], 0, 0, 0);
                }
            }
        }
    };

    // dual-target h1-segment (L0): gates1 into acc (W1, ksBase 5) AND
    // p into pacc (Wih2, ksBase 0) from the SAME A stream.
    auto segDual = [&](const bf16* A) {
        const int arow = wv * 16 + (lane & 15);
        const bf16* a0 = A + (size_t)arow * H_ + quad * 8;
        for (int blk = 0; blk < 32; blk += 16) {
            bf16x8 a0r[16];
#pragma unroll
            for (int i = 0; i < 16; ++i)
                a0r[i] = *(const bf16x8*)(a0 + (blk + i) * 32);
            __builtin_amdgcn_sched_barrier(0);
#pragma unroll
            for (int i = 0; i < 16; ++i) {
                int ig = blk + i;
                int c1 = (5 + ig) * 4 + quad;
                int cp = ig * 4 + quad;
#pragma unroll
                for (int t = 0; t < NT; ++t) {
                    int r = t * 16 + (lane & 15);
                    int cs1 = (c1 & ~15) | ((c1 ^ r) & 15);
                    bf16x8 b1 = *(const bf16x8*)(lds + (size_t)r * K1LDS + (cs1 << 3));
                    acc[t] = __builtin_amdgcn_mfma_f32_16x16x32_bf16(a0r[i], b1, acc[t], 0, 0, 0);
                    int csp = (cp & ~15) | ((cp ^ r) & 15);
                    bf16x8 bp = *(const bf16x8*)(ldsP + (size_t)r * KP + (csp << 3));
                    pacc[t] = __builtin_amdgcn_mfma_f32_16x16x32_bf16(a0r[i], bp, pacc[t], 0, 0, 0);
                }
            }
        }
    };

    // epilogue: shfl-gather gates, update creg, stage h to LDS, store h
    auto epilogue = [&](bf16* hw) {
        const int base = lane & 48;
#pragma unroll
        for (int r = 0; r < 4; ++r) {
            float vi = __shfl(acc[0][r], base + jj, 64);
            float vf = __shfl(acc[0][r], base + 8 + jj, 64);
            float vg = __shfl(acc[1][r], base + jj, 64);
            float vo = __shfl(acc[1][r], base + 8 + jj, 64);
            bool cond = (((lane >> 3) & 1) == (r & 1));
            int slot = r >> 1;
            if (cond) {
                float cv = creg[slot];
                float cn = sigmoidf_(vf + bias.y) * cv
                         + sigmoidf_(vi + bias.x) * tanhf(vg + bias.z);
                creg[slot] = cn;
                float hn = sigmoidf_(vo + bias.w) * tanhf(cn);
                hst[wv][quad * 4 + r][jj] = (bf16)hn;
            }
        }
        __syncthreads();
        if (lane < 32) {
            int row_l = lane >> 1, cg = lane & 1;
            ull v = *(const ull*)&hst[wv][row_l][cg * 4];
            __hip_atomic_store((ull*)(hw + (size_t)(wv * 16 + row_l) * H_ + n0h + cg * 4),
                               v, __ATOMIC_RELAXED, __HIP_MEMORY_SCOPE_AGENT);
        }
    };

    // prologue (L0): zero accs and pre-compute x(0) contribution
    if (layer == 0) {
#pragma unroll
        for (int t = 0; t < NT; ++t) {
            acc[t]  = (floatx4){0.f, 0.f, 0.f, 0.f};
            pacc[t] = (floatx4){0.f, 0.f, 0.f, 0.f};
        }
        seg1(xb, KX_, lds, K1LDS, IC<5>{}, 0);     // x(0)
    }

    for (int e = 0; e <= T_ + 1; ++e) {
        const int pm  = e % 3;            // p(e) write buffer
        const int pmr = (e + 2) % 3;      // p(e-1) read buffer
        float* const pbuf[3] = { p0, p1, p2 };

        if (layer == 0 && e <= T_) {
            // acc holds x(e) part (preloaded); dual-seg adds h1(e) part + p(e)
            const bf16* h1r = (e & 1) ? h1b1 : h1b0;          // h1^(e)
            segDual(h1r);

            // publish p(e) slice (f32, relaxed-agent write-through)
            float* pw = pbuf[pm] + (size_t)slice * B_ * NCOLS;
#pragma unroll
            for (int t = 0; t < NT; ++t)
#pragma unroll
                for (int r = 0; r < 4; ++r) {
                    int row = wv * 16 + quad * 4 + r;
                    __hip_atomic_store(pw + (size_t)row * NCOLS + t * 16 + (lane & 15),
                                       pacc[t][r], __ATOMIC_RELAXED, __HIP_MEMORY_SCOPE_AGENT);
                }

            if (e < T_) {
                bf16* hw = (e & 1) ? h1b0 : h1b1;              // h1^(e+1)
                epilogue(hw);
            }
        } else if (layer == 1 && e >= 2) {
#pragma unroll
            for (int t = 0; t < NT; ++t) acc[t] = (floatx4){0.f, 0.f, 0.f, 0.f};

            // prefetch p(e-1) slice into registers (post-fence: coherent)
            const float* pr = pbuf[pmr] + (size_t)slice * B_ * NCOLS;
            float pv[NT][4];
#pragma unroll
            for (int t = 0; t < NT; ++t)
#pragma unroll
                for (int r = 0; r < 4; ++r) {
                    int row = wv * 16 + quad * 4 + r;
                    pv[t][r] = pr[(size_t)row * NCOLS + t * 16 + (lane & 15)];
                }

            const bf16* h2r = (e & 1) ? h2b1 : h2b0;           // h2^(e-2)
            seg1(h2r, H_, lds, KP, IC<32>{}, 0);

#pragma unroll
            for (int t = 0; t < NT; ++t)
#pragma unroll
                for (int r = 0; r < 4; ++r) acc[t][r] += pv[t][r];

            bf16* hw = (e & 1) ? h2b0 : h2b1;                  // h2^(e-1)
            epilogue(hw);
        }

        // ---- decoupled group barrier ----
        asm volatile("s_waitcnt vmcnt(0)" ::: "memory");
        __syncthreads();
        const int etag = e + 1;
        if (tid == 0)
            __hip_atomic_fetch_add(cnt + line * CSTRIDE, 1u,
                                   __ATOMIC_RELAXED, __HIP_MEMORY_SCOPE_AGENT);
        // overlapped work in the barrier window (L0): next-epoch x-seg
        if (layer == 0 && e < T_) {
#pragma unroll
            for (int t = 0; t < NT; ++t) {
                acc[t]  = (floatx4){0.f, 0.f, 0.f, 0.f};
                pacc[t] = (floatx4){0.f, 0.f, 0.f, 0.f};
            }
            if (e + 1 < T_)
                seg1(xb + (size_t)(e + 1) * B_ * KX_, KX_, lds, K1LDS, IC<5>{}, 0);
        }
        if (layer == 0) {
            if (bid == 0) {
                if (tid < 16) {
                    const unsigned tgt = 8u * (unsigned)etag;
                    const unsigned* cp = cnt + tid * CSTRIDE;
                    while (__hip_atomic_load(cp, __ATOMIC_RELAXED, __HIP_MEMORY_SCOPE_AGENT) < tgt)
                        __builtin_amdgcn_s_sleep(1);
                }
                if (tid == 0)
                    __hip_atomic_store(cnt + L0FLAG * CSTRIDE, (unsigned)etag,
                                       __ATOMIC_RELAXED, __HIP_MEMORY_SCOPE_AGENT);
            } else if (tid == 0) {
                const unsigned* fp = cnt + L0FLAG * CSTRIDE;
                while (__hip_atomic_load(fp, __ATOMIC_RELAXED, __HIP_MEMORY_SCOPE_AGENT) < (unsigned)etag)
                    __builtin_amdgcn_s_sleep(1);
            }
            if (tid == 0 && etag >= 3) {   // slack-2 wait on L1 (p-buffer reuse)
                const unsigned* fp = cnt + L1FLAG * CSTRIDE;
                while (__hip_atomic_load(fp, __ATOMIC_RELAXED, __HIP_MEMORY_SCOPE_AGENT) < (unsigned)(etag - 2))
                    __builtin_amdgcn_s_sleep(1);
            }
        } else {
            if (bid == 8) {
                if (tid < 16) {
                    const unsigned tgt = 8u * (unsigned)etag;
                    const unsigned* cp = cnt + (16 + tid) * CSTRIDE;
                    while (__hip_atomic_load(cp, __ATOMIC_RELAXED, __HIP_MEMORY_SCOPE_AGENT) < tgt)
                        __builtin_amdgcn_s_sleep(1);
                }
                if (tid == 0)
                    __hip_atomic_store(cnt + L1FLAG * CSTRIDE, (unsigned)etag,
                                       __ATOMIC_RELAXED, __HIP_MEMORY_SCOPE_AGENT);
            } else if (tid == 0) {
                const unsigned* fp = cnt + L1FLAG * CSTRIDE;
                while (__hip_atomic_load(fp, __ATOMIC_RELAXED, __HIP_MEMORY_SCOPE_AGENT) < (unsigned)etag)
                    __builtin_amdgcn_s_sleep(1);
            }
            if (tid == 0) {                // zero-slack wait on L0 (p(e) ready)
                const unsigned* fp = cnt + L0FLAG * CSTRIDE;
                while (__hip_atomic_load(fp, __ATOMIC_RELAXED, __HIP_MEMORY_SCOPE_AGENT) < (unsigned)etag)
                    __builtin_amdgcn_s_sleep(1);
            }
        }
        __syncthreads();
        // acquire (cache inv) by wave 0 only
        if (tid < 64)
            __builtin_amdgcn_fence(__ATOMIC_ACQUIRE, "agent");
        __syncthreads();
    }

    // final join: everyone must see L1's last epoch (h2^(256)) before FC
    if (tid == 0 && layer == 0) {
        const unsigned* fp = cnt + L1FLAG * CSTRIDE;
        while (__hip_atomic_load(fp, __ATOMIC_RELAXED, __HIP_MEMORY_SCOPE_AGENT) < (unsigned)(T_ + 2))
            __builtin_amdgcn_s_sleep(1);
    }
    __syncthreads();
    if (tid < 64)
        __builtin_amdgcn_fence(__ATOMIC_ACQUIRE, "agent");
    __syncthreads();

    // ---- fused FC: out = h2^(256) @ Wfc^T + bfc ; h2^(256) is in h2b0 ----
    if (bid < B_) {
        const bf16* h2f = h2b0;
        for (int c = wv; c < C_; c += 8) {
            float a = 0.f;
            for (int k = lane; k < H_; k += 64)
                a += (float)h2f[(size_t)bid * H_ + k] * Wfc[(size_t)c * H_ + k];
#pragma unroll
            for (int off = 32; off; off >>= 1) a += __shfl_down(a, off, 64);
            if (lane == 0) out[bid * C_ + c] = a + bfc[c];
        }
    }
}

// ============ fallback: R13 VERBATIM (3548us proven, coupled barrier) =======
__global__ __launch_bounds__(512, 2)
void rnn_rebal8(const bf16* __restrict__ xb,
                bf16* __restrict__ h1b0, bf16* __restrict__ h1b1,
                bf16* __restrict__ h2b0, bf16* __restrict__ h2b1,
                float* __restrict__ p0, float* __restrict__ p1,
                const float* __restrict__ c1in, const float* __restrict__ c2in,
                const float* __restrict__ Wih1, const float* __restrict__ Whh1,
                const float* __restrict__ bih1, const float* __restrict__ bhh1,
                const float* __restrict__ Wih2, const float* __restrict__ Whh2,
                const float* __restrict__ bih2, const float* __restrict__ bhh2,
                const float* __restrict__ Wfc, const float* __restrict__ bfc,
                float* __restrict__ out, unsigned* __restrict__ cnt, int nblk)
{
    extern __shared__ bf16 lds[];
    __shared__ __align__(16) bf16 hst[8][16][NHC];

    const int tid   = threadIdx.x;
    const int bid   = blockIdx.x;
    const int layer = (bid >> 3) & 1;
    const int slice = (bid & 7) | ((bid >> 4) << 3);
    const int n0h   = slice * NHC;
    const int arr_per_line = nblk >> 4;
    bf16* ldsP = lds + 32 * K1LDS;

    stage_rebal(lds, ldsP, tid, layer, n0h, Wih1, Whh1, Wih2, Whh2);
    __syncthreads();

    const int lane = tid & 63;
    const int wv   = tid >> 6;
    const int jj   = lane & (NHC - 1);
    const int quad = lane >> 4;

    float4 bias;
    {
        const float* bi = layer ? bih2 : bih1;
        const float* bh = layer ? bhh2 : bhh1;
        int col = n0h + jj;
        bias.x = bi[col] + bh[col];
        bias.y = bi[col + H_] + bh[col + H_];
        bias.z = bi[col + 2 * H_] + bh[col + 2 * H_];
        bias.w = bi[col + 3 * H_] + bh[col + 3 * H_];
    }

    float creg[2];
    {
        const float* cin = layer ? c2in : c1in;
        int dup = (lane >> 3) & 1;
#pragma unroll
        for (int rp = 0; rp < 2; ++rp) {
            int row = wv * 16 + quad * 4 + rp * 2 + dup;
            creg[rp] = cin[(size_t)row * H_ + n0h + jj];
        }
    }

    floatx4 acc[NT];
    floatx4 pacc[NT];

    auto seg1 = [&](const bf16* A, int ldA, const bf16* Bb, int ldB,
                    auto nksC, int ksBase) {
        constexpr int NKS = decltype(nksC)::value;
        constexpr int CH  = NKS < 16 ? NKS : 16;
        const int arow = wv * 16 + (lane & 15);
        const bf16* a0 = A + (size_t)arow * ldA + quad * 8;
        for (int blk = 0; blk < NKS; blk += CH) {
            bf16x8 a0r[CH];
#pragma unroll
            for (int i = 0; i < CH; ++i)
                a0r[i] = *(const bf16x8*)(a0 + (blk + i) * 32);
            __builtin_amdgcn_sched_barrier(0);
#pragma unroll
            for (int i = 0; i < CH; ++i) {
                int c = (ksBase + blk + i) * 4 + quad;
#pragma unroll
                for (int t = 0; t < NT; ++t) {
                    int r = t * 16 + (lane & 15);
                    int cs = (c & ~15) | ((c ^ r) & 15);
                    bf16x8 bfr = *(const bf16x8*)(Bb + (size_t)r * ldB + (cs << 3));
                    acc[t] = __builtin_amdgcn_mfma_f32_16x16x32_bf16(a0r[i], bfr, acc[t], 0, 0, 0);
                }
            }
        }
    };

    auto segDual = [&](const bf16* A) {
        const int arow = wv * 16 + (lane & 15);
        const bf16* a0 = A + (size_t)arow * H_ + quad * 8;
        for (int blk = 0; blk < 32; blk += 16) {
            bf16x8 a0r[16];
#pragma unroll
            for (int i = 0; i < 16; ++i)
                a0r[i] = *(const bf16x8*)(a0 + (blk + i) * 32);
            __builtin_amdgcn_sched_barrier(0);
#pragma unroll
            for (int i = 0; i < 16; ++i) {
                int ig = blk + i;
                int c1 = (5 + ig) * 4 + quad;
                int cp = ig * 4 + quad;
#pragma unroll
                for (int t = 0; t < NT; ++t) {
                    int r = t * 16 + (lane & 15);
                    int cs1 = (c1 & ~15) | ((c1 ^ r) & 15);
                    bf16x8 b1 = *(const bf16x8*)(lds + (size_t)r * K1LDS + (cs1 << 3));
                    acc[t] = __builtin_amdgcn_mfma_f32_16x16x32_bf16(a0r[i], b1, acc[t], 0, 0, 0);
                    int csp = (cp & ~15) | ((cp ^ r) & 15);
                    bf16x8 bp = *(const bf16x8*)(ldsP + (size_t)r * KP + (csp << 3));
                    pacc[t] = __builtin_amdgcn_mfma_f32_16x16x32_bf16(a0r[i], bp, pacc[t], 0, 0, 0);
                }
            }
        }
    };

    auto epilogue = [&](bf16* hw) {
        const int base = lane & 48;
#pragma unroll
        for (int r = 0; r < 4; ++r) {
            float vi = __shfl(acc[0][r], base + jj, 64);
            float vf = __shfl(acc[0][r], base + 8 + jj, 64);
            float vg = __shfl(acc[1][r], base + jj, 64);
            float vo = __shfl(acc[1][r], base + 8 + jj, 64);
            bool cond = (((lane >> 3) & 1) == (r & 1));
            int slot = r >> 1;
            if (cond) {
                float cv = creg[slot];
                float cn = sigmoidf_(vf + bias.y) * cv
                         + sigmoidf_(vi + bias.x) * tanhf(vg + bias.z);
                creg[slot] = cn;
                float hn = sigmoidf_(vo + bias.w) * tanhf(cn);
                hst[wv][quad * 4 + r][jj] = (bf16)hn;
            }
        }
        __syncthreads();
        if (lane < 32) {
            int row_l = lane >> 1, cg = lane & 1;
            ull v = *(const ull*)&hst[wv][row_l][cg * 4];
            __hip_atomic_store((ull*)(hw + (size_t)(wv * 16 + row_l) * H_ + n0h + cg * 4),
                               v, __ATOMIC_RELAXED, __HIP_MEMORY_SCOPE_AGENT);
        }
    };

    if (layer == 0) {
#pragma unroll
        for (int t = 0; t < NT; ++t) {
            acc[t]  = (floatx4){0.f, 0.f, 0.f, 0.f};
            pacc[t] = (floatx4){0.f, 0.f, 0.f, 0.f};
        }
        seg1(xb, KX_, lds, K1LDS, IC<5>{}, 0);
    }

    for (int e = 0; e <= T_ + 1; ++e) {
        if (layer == 0 && e <= T_) {
            const bf16* h1r = (e & 1) ? h1b1 : h1b0;
            segDual(h1r);

            float* pw = ((e & 1) ? p1 : p0) + (size_t)slice * B_ * NCOLS;
#pragma unroll
            for (int t = 0; t < NT; ++t)
#pragma unroll
                for (int r = 0; r < 4; ++r) {
                    int row = wv * 16 + quad * 4 + r;
                    __hip_atomic_store(pw + (size_t)row * NCOLS + t * 16 + (lane & 15),
                                       pacc[t][r], __ATOMIC_RELAXED, __HIP_MEMORY_SCOPE_AGENT);
                }

            if (e < T_) {
                bf16* hw = (e & 1) ? h1b0 : h1b1;
                epilogue(hw);
            }
        } else if (layer == 1 && e >= 2) {
#pragma unroll
            for (int t = 0; t < NT; ++t) acc[t] = (floatx4){0.f, 0.f, 0.f, 0.f};

            const float* pr = ((e & 1) ? p0 : p1) + (size_t)slice * B_ * NCOLS;
            float pv[NT][4];
#pragma unroll
            for (int t = 0; t < NT; ++t)
#pragma unroll
                for (int r = 0; r < 4; ++r) {
                    int row = wv * 16 + quad * 4 + r;
                    pv[t][r] = pr[(size_t)row * NCOLS + t * 16 + (lane & 15)];
                }

            const bf16* h2r = (e & 1) ? h2b1 : h2b0;
            seg1(h2r, H_, lds, KP, IC<32>{}, 0);

#pragma unroll
            for (int t = 0; t < NT; ++t)
#pragma unroll
                for (int r = 0; r < 4; ++r) acc[t][r] += pv[t][r];

            bf16* hw = (e & 1) ? h2b0 : h2b1;
            epilogue(hw);
        }

        asm volatile("s_waitcnt vmcnt(0)" ::: "memory");
        __syncthreads();
        const unsigned etag = (unsigned)(e + 1);
        if (tid == 0)
            __hip_atomic_fetch_add(cnt + (bid & 15) * CSTRIDE, 1u,
                                   __ATOMIC_RELAXED, __HIP_MEMORY_SCOPE_AGENT);
        if (layer == 0 && e < T_) {
#pragma unroll
            for (int t = 0; t < NT; ++t) {
                acc[t]  = (floatx4){0.f, 0.f, 0.f, 0.f};
                pacc[t] = (floatx4){0.f, 0.f, 0.f, 0.f};
            }
            if (e + 1 < T_)
                seg1(xb + (size_t)(e + 1) * B_ * KX_, KX_, lds, K1LDS, IC<5>{}, 0);
        }
        if (bid == 0) {
            if (tid < 16) {
                const unsigned tgt = etag * (unsigned)arr_per_line;
                const unsigned* cp = cnt + tid * CSTRIDE;
                while (__hip_atomic_load(cp, __ATOMIC_RELAXED, __HIP_MEMORY_SCOPE_AGENT) < tgt)
                    __builtin_amdgcn_s_sleep(1);
            }
            if (tid == 0)
                __hip_atomic_store(cnt + FLAGLINE * CSTRIDE, etag,
                                   __ATOMIC_RELAXED, __HIP_MEMORY_SCOPE_AGENT);
        } else {
            if (tid == 0) {
                const unsigned* fp = cnt + FLAGLINE * CSTRIDE;
                while (__hip_atomic_load(fp, __ATOMIC_RELAXED, __HIP_MEMORY_SCOPE_AGENT) < etag)
                    __builtin_amdgcn_s_sleep(1);
            }
        }
        __syncthreads();
        if (tid < 64)
            __builtin_amdgcn_fence(__ATOMIC_ACQUIRE, "agent");
        __syncthreads();
    }

    if (bid < B_) {
        const bf16* h2f = h2b0;
        for (int c = wv; c < C_; c += 8) {
            float a = 0.f;
            for (int k = lane; k < H_; k += 64)
                a += (float)h2f[(size_t)bid * H_ + k] * Wfc[(size_t)c * H_ + k];
#pragma unroll
            for (int off = 32; off; off >>= 1) a += __shfl_down(a, off, 64);
            if (lane == 0) out[bid * C_ + c] = a + bfc[c];
        }
    }
}

extern "C" void kernel_launch(void* const* d_in, const int* in_sizes, int n_in,
                              void* d_out, int out_size, void* d_ws, size_t ws_size,
                              hipStream_t stream)
{
    const float* x    = (const float*)d_in[0];
    const float* h1in = (const float*)d_in[1];
    const float* c1in = (const float*)d_in[2];
    const float* h2in = (const float*)d_in[3];
    const float* c2in = (const float*)d_in[4];
    const float* Wih1 = (const float*)d_in[5];
    const float* Whh1 = (const float*)d_in[6];
    const float* bih1 = (const float*)d_in[7];
    const float* bhh1 = (const float*)d_in[8];
    const float* Wih2 = (const float*)d_in[9];
    const float* Whh2 = (const float*)d_in[10];
    const float* bih2 = (const float*)d_in[11];
    const float* bhh2 = (const float*)d_in[12];
    const float* Wfc  = (const float*)d_in[13];
    const float* bfc  = (const float*)d_in[14];
    float* out = (float*)d_out;

    const size_t szXB  = (size_t)T_ * B_ * KX_ * 2;        // 10485760
    const size_t szH   = (size_t)B_ * H_ * 2;              // 262144
    const size_t szCnt = (size_t)NLINES * CSTRIDE * 4;     // 10240
    const size_t szP   = (size_t)128 * B_ * NCOLS * 4;     // 2097152
    const size_t needR13 = szXB + 4 * szH + szCnt + 2 * szP;
    const size_t needDec = szXB + 4 * szH + szCnt + 3 * szP;

    char* p = (char*)d_ws;
    bf16* xb = (bf16*)p;    p += szXB;
    bf16* h1b0 = (bf16*)p;  p += szH;
    bf16* h1b1 = (bf16*)p;  p += szH;
    bf16* h2b0 = (bf16*)p;  p += szH;
    bf16* h2b1 = (bf16*)p;  p += szH;
    unsigned* cnt = (unsigned*)p;  p += szCnt;
    float* p0 = (float*)p;  p += szP;
    float* p1 = (float*)p;  p += szP;
    float* p2 = (float*)p;

    const size_t citems = (size_t)T_ * B_ * KX_ + 2 * (size_t)B_ * H_ + NLINES * CSTRIDE;
    convert_all<<<(int)((citems + 255) / 256), 256, 0, stream>>>(
        x, h1in, h2in, xb, h1b0, h2b0, cnt);

    int nblk = 256;
    void* argsDec[] = { &xb, &h1b0, &h1b1, &h2b0, &h2b1, &p0, &p1, &p2,
                        (void*)&c1in, (void*)&c2in,
                        (void*)&Wih1, (void*)&Whh1, (void*)&bih1, (void*)&bhh1,
                        (void*)&Wih2, (void*)&Whh2, (void*)&bih2, (void*)&bhh2,
                        (void*)&Wfc, (void*)&bfc, &out, &cnt, &nblk };
    void* argsR13[] = { &xb, &h1b0, &h1b1, &h2b0, &h2b1, &p0, &p1,
                        (void*)&c1in, (void*)&c2in,
                        (void*)&Wih1, (void*)&Whh1, (void*)&bih1, (void*)&bhh1,
                        (void*)&Wih2, (void*)&Whh2, (void*)&bih2, (void*)&bhh2,
                        (void*)&Wfc, (void*)&bfc, &out, &cnt, &nblk };

    const unsigned ldsRebal = (unsigned)(32 * K1LDS + 32 * KP) * 2u;  // 147456
    hipError_t err = hipErrorOutOfMemory;
    if (ws_size >= needDec) {
        if (hipFuncSetAttribute((const void*)rnn_decoup8,
                                hipFuncAttributeMaxDynamicSharedMemorySize,
                                (int)ldsRebal) == hipSuccess) {
            err = hipLaunchCooperativeKernel((const void*)rnn_decoup8,
                                             dim3(256), dim3(512), argsDec,
                                             ldsRebal, stream);
        }
    }
    if (err != hipSuccess && ws_size >= needR13) {
        (void)hipGetLastError();
        if (hipFuncSetAttribute((const void*)rnn_rebal8,
                                hipFuncAttributeMaxDynamicSharedMemorySize,
                                (int)ldsRebal) == hipSuccess) {
            (void)hipLaunchCooperativeKernel((const void*)rnn_rebal8,
                                             dim3(256), dim3(512), argsR13,
                                             ldsRebal, stream);
        }
    }
}

// Round 11
// 3329.280 us; speedup vs baseline: 1.4611x; 1.0002x over previous
//
#include <hip/hip_runtime.h>
#include <math.h>

// stacked_rnn R17: R16 (decoupled group barriers, 3330us proven) + distributed
// detect. The aggregator block (bid0/bid8) is a structural straggler: it leaves
// the barrier ~2 LLC RTs after everyone (observe last arrival + post flag),
// so its own next arrival is late and the whole group waits on it -> cascade.
// R17: every block's wave 0 polls all 32 arrival lines directly (lanes 0..15:
// own group @ 8*etag; lanes 16..31: other group @ slack target) + __all reduce.
// Removes aggregator hop, flag line, straggler cascade, and one syncthreads
// (poll + acquire fence both in wave 0 before a single join). Flood: 256
// readers/line (R7's failure was 2048/line). Semantics identical otherwise.
// Fallback = R16 primary VERBATIM (aggregator + flags).

typedef __bf16 bf16;
typedef __bf16 bf16x8 __attribute__((ext_vector_type(8)));
typedef float floatx4 __attribute__((ext_vector_type(4)));
typedef unsigned long long ull;

#define B_   128
#define T_   256
#define H_   1024
#define I_   150
#define KX_  160
#define C_   60
#define K1LDS 1280   // L0 W1 LDS row width in elems (x 160 + h1 1024 + pad)
#define KP    1024   // Wih2 / Whh2 LDS row width
#define NLINES 40    // zeroed counter lines (0..31 arrivals, 32/33 flags for fallback)
#define CSTRIDE 64   // uints between lines (256B)
#define L0FLAG 32    // fallback: L0 group flag line
#define L1FLAG 33    // fallback: L1 group flag line
#define NCOLS 32     // gate-cols per block tile
#define NHC  8       // h-cols per block (NCOLS/4)
#define NT   2       // N-tiles of 16

template<int N> struct IC { static constexpr int value = N; };

__device__ __forceinline__ float sigmoidf_(float x) { return 1.f / (1.f + expf(-x)); }

// ---------------- conversion / init kernel ----------------
__global__ __launch_bounds__(256)
void convert_all(const float* __restrict__ x,
                 const float* __restrict__ h1in, const float* __restrict__ h2in,
                 bf16* __restrict__ xb, bf16* __restrict__ h1b0, bf16* __restrict__ h2b0,
                 unsigned* __restrict__ cnt)
{
    const size_t nXB = (size_t)T_ * B_ * KX_;   // 5242880
    const size_t nHC = (size_t)B_ * H_;         // 131072
    size_t idx = (size_t)blockIdx.x * 256 + threadIdx.x;

    if (idx < nXB) {                            // x [B][T][150] -> xb [T][B][160]
        size_t t = idx / (B_ * KX_);
        size_t r = idx - t * (B_ * KX_);
        size_t b = r / KX_, k = r - b * KX_;
        xb[idx] = (k < I_) ? (bf16)x[(b * T_ + t) * I_ + k] : (bf16)0.f;
        return;
    }
    idx -= nXB;
    if (idx < nHC) { h1b0[idx] = (bf16)h1in[idx]; return; }
    idx -= nHC;
    if (idx < nHC) { h2b0[idx] = (bf16)h2in[idx]; return; }
    idx -= nHC;
    if (idx < NLINES * CSTRIDE) cnt[idx] = 0u;
}

// ---- shared staging helper (both persistent kernels, 512 threads) ----
__device__ __forceinline__ void stage_rebal(
    bf16* lds, bf16* ldsP, int tid, int layer, int n0h,
    const float* Wih1, const float* Whh1, const float* Wih2, const float* Whh2)
{
    if (layer == 0) {
        {   // W1 region: 32 rows x K1LDS (x [0,160), h1 [160,1184), pad)
            const int cpr = K1LDS >> 3;           // 160
            const int total = NCOLS * cpr;
            for (int ci = tid; ci < total; ci += 512) {
                int r = ci / cpr, c = ci - r * cpr;
                int g = r / NHC, j = r - g * NHC;
                int grow = (g << 10) + n0h + j;
                int k0 = c << 3;
                float v[8];
#pragma unroll
                for (int u = 0; u < 8; ++u) {
                    int k = k0 + u;
                    v[u] = (k < I_) ? Wih1[(size_t)grow * I_ + k]
                         : (k < KX_) ? 0.f
                         : (k < KX_ + H_) ? Whh1[(size_t)grow * H_ + (k - KX_)] : 0.f;
                }
                int cs = (c & ~15) | ((c ^ r) & 15);
                bf16* dst = lds + (size_t)r * K1LDS + (cs << 3);
#pragma unroll
                for (int u = 0; u < 8; ++u) dst[u] = (bf16)v[u];
            }
        }
        {   // Wih2 region: 32 rows x KP
            const int cpr = KP >> 3;              // 128
            const int total = NCOLS * cpr;
            for (int ci = tid; ci < total; ci += 512) {
                int r = ci / cpr, c = ci - r * cpr;
                int g = r / NHC, j = r - g * NHC;
                int grow = (g << 10) + n0h + j;
                int k0 = c << 3;
                float v[8];
#pragma unroll
                for (int u = 0; u < 8; ++u) v[u] = Wih2[(size_t)grow * H_ + k0 + u];
                int cs = (c & ~15) | ((c ^ r) & 15);
                bf16* dst = ldsP + (size_t)r * KP + (cs << 3);
#pragma unroll
                for (int u = 0; u < 8; ++u) dst[u] = (bf16)v[u];
            }
        }
    } else {
        // Whh2 region: 32 rows x KP
        const int cpr = KP >> 3;
        const int total = NCOLS * cpr;
        for (int ci = tid; ci < total; ci += 512) {
            int r = ci / cpr, c = ci - r * cpr;
            int g = r / NHC, j = r - g * NHC;
            int grow = (g << 10) + n0h + j;
            int k0 = c << 3;
            float v[8];
#pragma unroll
            for (int u = 0; u < 8; ++u) v[u] = Whh2[(size_t)grow * H_ + k0 + u];
            int cs = (c & ~15) | ((c ^ r) & 15);
            bf16* dst = lds + (size_t)r * KP + (cs << 3);
#pragma unroll
            for (int u = 0; u < 8; ++u) dst[u] = (bf16)v[u];
        }
    }
}

// ================= R17 primary: distributed-detect decoupled kernel =========
// 256 blocks = 2 layers x 128 slices. layer=(bid>>3)&1, slice=(bid&7)|((bid>>4)<<3).
// Arrival line: layer*16 + ((bid&7) | (((bid>>4)&1)<<3)) -> 8 blocks/line.
// Wave-0 distributed detect: lane<16 own-group line @ 8*etag; lane 16..31
// other-group line @ slack (L0: 8*(etag-2) for p-buffer reuse; L1: 8*etag
// for p(e) visibility). p triple-buffered: write p[e%3], read p[(e+2)%3].
__global__ __launch_bounds__(512, 2)
void rnn_dist8(const bf16* __restrict__ xb,
               bf16* __restrict__ h1b0, bf16* __restrict__ h1b1,
               bf16* __restrict__ h2b0, bf16* __restrict__ h2b1,
               float* __restrict__ p0, float* __restrict__ p1, float* __restrict__ p2,
               const float* __restrict__ c1in, const float* __restrict__ c2in,
               const float* __restrict__ Wih1, const float* __restrict__ Whh1,
               const float* __restrict__ bih1, const float* __restrict__ bhh1,
               const float* __restrict__ Wih2, const float* __restrict__ Whh2,
               const float* __restrict__ bih2, const float* __restrict__ bhh2,
               const float* __restrict__ Wfc, const float* __restrict__ bfc,
               float* __restrict__ out, unsigned* __restrict__ cnt, int nblk)
{
    extern __shared__ bf16 lds[];
    __shared__ __align__(16) bf16 hst[8][16][NHC];   // epilogue staging

    const int tid   = threadIdx.x;
    const int bid   = blockIdx.x;
    const int layer = (bid >> 3) & 1;
    const int slice = (bid & 7) | ((bid >> 4) << 3);
    const int n0h   = slice * NHC;
    const int line  = layer * 16 + ((bid & 7) | (((bid >> 4) & 1) << 3));
    bf16* ldsP = lds + 32 * K1LDS;               // L0's Wih2 region

    stage_rebal(lds, ldsP, tid, layer, n0h, Wih1, Whh1, Wih2, Whh2);
    __syncthreads();

    const int lane = tid & 63;
    const int wv   = tid >> 6;          // 0..7
    const int jj   = lane & (NHC - 1);
    const int quad = lane >> 4;

    float4 bias;
    {
        const float* bi = layer ? bih2 : bih1;
        const float* bh = layer ? bhh2 : bhh1;
        int col = n0h + jj;
        bias.x = bi[col] + bh[col];
        bias.y = bi[col + H_] + bh[col + H_];
        bias.z = bi[col + 2 * H_] + bh[col + 2 * H_];
        bias.w = bi[col + 3 * H_] + bh[col + 3 * H_];
    }

    float creg[2];
    {
        const float* cin = layer ? c2in : c1in;
        int dup = (lane >> 3) & 1;
#pragma unroll
        for (int rp = 0; rp < 2; ++rp) {
            int row = wv * 16 + quad * 4 + rp * 2 + dup;
            creg[rp] = cin[(size_t)row * H_ + n0h + jj];
        }
    }

    floatx4 acc[NT];
    floatx4 pacc[NT];

    // generic single-target K-segment (CH=16, proven)
    auto seg1 = [&](const bf16* A, int ldA, const bf16* Bb, int ldB,
                    auto nksC, int ksBase) {
        constexpr int NKS = decltype(nksC)::value;
        constexpr int CH  = NKS < 16 ? NKS : 16;
        const int arow = wv * 16 + (lane & 15);
        const bf16* a0 = A + (size_t)arow * ldA + quad * 8;
        for (int blk = 0; blk < NKS; blk += CH) {
            bf16x8 a0r[CH];
#pragma unroll
            for (int i = 0; i < CH; ++i)
                a0r[i] = *(const bf16x8*)(a0 + (blk + i) * 32);
            __builtin_amdgcn_sched_barrier(0);
#pragma unroll
            for (int i = 0; i < CH; ++i) {
                int c = (ksBase + blk + i) * 4 + quad;
#pragma unroll
                for (int t = 0; t < NT; ++t) {
                    int r = t * 16 + (lane & 15);
                    int cs = (c & ~15) | ((c ^ r) & 15);
                    bf16x8 bfr = *(const bf16x8*)(Bb + (size_t)r * ldB + (cs << 3));
                    acc[t] = __builtin_amdgcn_mfma_f32_16x16x32_bf16(a0r[i], bfr, acc[t], 0, 0, 0);
                }
            }
        }
    };

    // dual-target h1-segment (L0): gates1 into acc (W1, ksBase 5) AND
    // p into pacc (Wih2, ksBase 0) from the SAME A stream.
    auto segDual = [&](const bf16* A) {
        const int arow = wv * 16 + (lane & 15);
        const bf16* a0 = A + (size_t)arow * H_ + quad * 8;
        for (int blk = 0; blk < 32; blk += 16) {
            bf16x8 a0r[16];
#pragma unroll
            for (int i = 0; i < 16; ++i)
                a0r[i] = *(const bf16x8*)(a0 + (blk + i) * 32);
            __builtin_amdgcn_sched_barrier(0);
#pragma unroll
            for (int i = 0; i < 16; ++i) {
                int ig = blk + i;
                int c1 = (5 + ig) * 4 + quad;
                int cp = ig * 4 + quad;
#pragma unroll
                for (int t = 0; t < NT; ++t) {
                    int r = t * 16 + (lane & 15);
                    int cs1 = (c1 & ~15) | ((c1 ^ r) & 15);
                    bf16x8 b1 = *(const bf16x8*)(lds + (size_t)r * K1LDS + (cs1 << 3));
                    acc[t] = __builtin_amdgcn_mfma_f32_16x16x32_bf16(a0r[i], b1, acc[t], 0, 0, 0);
                    int csp = (cp & ~15) | ((cp ^ r) & 15);
                    bf16x8 bp = *(const bf16x8*)(ldsP + (size_t)r * KP + (csp << 3));
                    pacc[t] = __builtin_amdgcn_mfma_f32_16x16x32_bf16(a0r[i], bp, pacc[t], 0, 0, 0);
                }
            }
        }
    };

    // epilogue: shfl-gather gates, update creg, stage h to LDS, store h
    auto epilogue = [&](bf16* hw) {
        const int base = lane & 48;
#pragma unroll
        for (int r = 0; r < 4; ++r) {
            float vi = __shfl(acc[0][r], base + jj, 64);
            float vf = __shfl(acc[0][r], base + 8 + jj, 64);
            float vg = __shfl(acc[1][r], base + jj, 64);
            float vo = __shfl(acc[1][r], base + 8 + jj, 64);
            bool cond = (((lane >> 3) & 1) == (r & 1));
            int slot = r >> 1;
            if (cond) {
                float cv = creg[slot];
                float cn = sigmoidf_(vf + bias.y) * cv
                         + sigmoidf_(vi + bias.x) * tanhf(vg + bias.z);
                creg[slot] = cn;
                float hn = sigmoidf_(vo + bias.w) * tanhf(cn);
                hst[wv][quad * 4 + r][jj] = (bf16)hn;
            }
        }
        __syncthreads();
        if (lane < 32) {
            int row_l = lane >> 1, cg = lane & 1;
            ull v = *(const ull*)&hst[wv][row_l][cg * 4];
            __hip_atomic_store((ull*)(hw + (size_t)(wv * 16 + row_l) * H_ + n0h + cg * 4),
                               v, __ATOMIC_RELAXED, __HIP_MEMORY_SCOPE_AGENT);
        }
    };

    // prologue (L0): zero accs and pre-compute x(0) contribution
    if (layer == 0) {
#pragma unroll
        for (int t = 0; t < NT; ++t) {
            acc[t]  = (floatx4){0.f, 0.f, 0.f, 0.f};
            pacc[t] = (floatx4){0.f, 0.f, 0.f, 0.f};
        }
        seg1(xb, KX_, lds, K1LDS, IC<5>{}, 0);     // x(0)
    }

    for (int e = 0; e <= T_ + 1; ++e) {
        const int pm  = e % 3;            // p(e) write buffer
        const int pmr = (e + 2) % 3;      // p(e-1) read buffer
        float* const pbuf[3] = { p0, p1, p2 };

        if (layer == 0 && e <= T_) {
            // acc holds x(e) part (preloaded); dual-seg adds h1(e) part + p(e)
            const bf16* h1r = (e & 1) ? h1b1 : h1b0;          // h1^(e)
            segDual(h1r);

            // publish p(e) slice (f32, relaxed-agent write-through)
            float* pw = pbuf[pm] + (size_t)slice * B_ * NCOLS;
#pragma unroll
            for (int t = 0; t < NT; ++t)
#pragma unroll
                for (int r = 0; r < 4; ++r) {
                    int row = wv * 16 + quad * 4 + r;
                    __hip_atomic_store(pw + (size_t)row * NCOLS + t * 16 + (lane & 15),
                                       pacc[t][r], __ATOMIC_RELAXED, __HIP_MEMORY_SCOPE_AGENT);
                }

            if (e < T_) {
                bf16* hw = (e & 1) ? h1b0 : h1b1;              // h1^(e+1)
                epilogue(hw);
            }
        } else if (layer == 1 && e >= 2) {
#pragma unroll
            for (int t = 0; t < NT; ++t) acc[t] = (floatx4){0.f, 0.f, 0.f, 0.f};

            // prefetch p(e-1) slice into registers (post-fence: coherent)
            const float* pr = pbuf[pmr] + (size_t)slice * B_ * NCOLS;
            float pv[NT][4];
#pragma unroll
            for (int t = 0; t < NT; ++t)
#pragma unroll
                for (int r = 0; r < 4; ++r) {
                    int row = wv * 16 + quad * 4 + r;
                    pv[t][r] = pr[(size_t)row * NCOLS + t * 16 + (lane & 15)];
                }

            const bf16* h2r = (e & 1) ? h2b1 : h2b0;           // h2^(e-2)
            seg1(h2r, H_, lds, KP, IC<32>{}, 0);

#pragma unroll
            for (int t = 0; t < NT; ++t)
#pragma unroll
                for (int r = 0; r < 4; ++r) acc[t][r] += pv[t][r];

            bf16* hw = (e & 1) ? h2b0 : h2b1;                  // h2^(e-1)
            epilogue(hw);
        }

        // ---- barrier: arrive -> overlapped x-seg -> distributed detect+fence
        asm volatile("s_waitcnt vmcnt(0)" ::: "memory");
        __syncthreads();
        const int etag = e + 1;
        if (tid == 0)
            __hip_atomic_fetch_add(cnt + line * CSTRIDE, 1u,
                                   __ATOMIC_RELAXED, __HIP_MEMORY_SCOPE_AGENT);
        // overlapped work in the barrier window (L0): next-epoch x-seg
        if (layer == 0 && e < T_) {
#pragma unroll
            for (int t = 0; t < NT; ++t) {
                acc[t]  = (floatx4){0.f, 0.f, 0.f, 0.f};
                pacc[t] = (floatx4){0.f, 0.f, 0.f, 0.f};
            }
            if (e + 1 < T_)
                seg1(xb + (size_t)(e + 1) * B_ * KX_, KX_, lds, K1LDS, IC<5>{}, 0);
        }
        // distributed detect in wave 0: lanes 0..15 own group, 16..31 other
        if (tid < 64) {
            const unsigned* cp = nullptr;
            unsigned tgt = 0;
            if (lane < 16) {
                cp = cnt + (layer * 16 + lane) * CSTRIDE;
                tgt = 8u * (unsigned)etag;
            } else if (lane < 32) {
                if (layer == 0) {
                    if (etag >= 3) {               // slack-2 on L1 (p reuse)
                        cp = cnt + (16 + (lane - 16)) * CSTRIDE;
                        tgt = 8u * (unsigned)(etag - 2);
                    }
                } else {                           // exact on L0 (p visibility)
                    cp = cnt + (lane - 16) * CSTRIDE;
                    tgt = 8u * (unsigned)etag;
                }
            }
            for (;;) {
                bool ok = (cp == nullptr) ||
                          (__hip_atomic_load(cp, __ATOMIC_RELAXED,
                                             __HIP_MEMORY_SCOPE_AGENT) >= tgt);
                if (__all(ok)) break;
                __builtin_amdgcn_s_sleep(1);
            }
            // acquire (cache inv) by wave 0 only
            __builtin_amdgcn_fence(__ATOMIC_ACQUIRE, "agent");
        }
        __syncthreads();
    }

    // final join: all blocks must see L1's last epoch (h2^(256)) before FC
    if (tid < 64) {
        if (lane < 16) {
            const unsigned* cp = cnt + (16 + lane) * CSTRIDE;
            while (__hip_atomic_load(cp, __ATOMIC_RELAXED,
                                     __HIP_MEMORY_SCOPE_AGENT) < 8u * (unsigned)(T_ + 2))
                __builtin_amdgcn_s_sleep(1);
        }
        __builtin_amdgcn_fence(__ATOMIC_ACQUIRE, "agent");
    }
    __syncthreads();

    // ---- fused FC: out = h2^(256) @ Wfc^T + bfc ; h2^(256) is in h2b0 ----
    if (bid < B_) {
        const bf16* h2f = h2b0;
        for (int c = wv; c < C_; c += 8) {
            float a = 0.f;
            for (int k = lane; k < H_; k += 64)
                a += (float)h2f[(size_t)bid * H_ + k] * Wfc[(size_t)c * H_ + k];
#pragma unroll
            for (int off = 32; off; off >>= 1) a += __shfl_down(a, off, 64);
            if (lane == 0) out[bid * C_ + c] = a + bfc[c];
        }
    }
}

// ============ fallback: R16 primary VERBATIM (3330us proven) ================
__global__ __launch_bounds__(512, 2)
void rnn_decoup8(const bf16* __restrict__ xb,
                 bf16* __restrict__ h1b0, bf16* __restrict__ h1b1,
                 bf16* __restrict__ h2b0, bf16* __restrict__ h2b1,
                 float* __restrict__ p0, float* __restrict__ p1, float* __restrict__ p2,
                 const float* __restrict__ c1in, const float* __restrict__ c2in,
                 const float* __restrict__ Wih1, const float* __restrict__ Whh1,
                 const float* __restrict__ bih1, const float* __restrict__ bhh1,
                 const float* __restrict__ Wih2, const float* __restrict__ Whh2,
                 const float* __restrict__ bih2, const float* __restrict__ bhh2,
                 const float* __restrict__ Wfc, const float* __restrict__ bfc,
                 float* __restrict__ out, unsigned* __restrict__ cnt, int nblk)
{
    extern __shared__ bf16 lds[];
    __shared__ __align__(16) bf16 hst[8][16][NHC];

    const int tid   = threadIdx.x;
    const int bid   = blockIdx.x;
    const int layer = (bid >> 3) & 1;
    const int slice = (bid & 7) | ((bid >> 4) << 3);
    const int n0h   = slice * NHC;
    const int line  = layer * 16 + ((bid & 7) | (((bid >> 4) & 1) << 3));
    bf16* ldsP = lds + 32 * K1LDS;

    stage_rebal(lds, ldsP, tid, layer, n0h, Wih1, Whh1, Wih2, Whh2);
    __syncthreads();

    const int lane = tid & 63;
    const int wv   = tid >> 6;
    const int jj   = lane & (NHC - 1);
    const int quad = lane >> 4;

    float4 bias;
    {
        const float* bi = layer ? bih2 : bih1;
        const float* bh = layer ? bhh2 : bhh1;
        int col = n0h + jj;
        bias.x = bi[col] + bh[col];
        bias.y = bi[col + H_] + bh[col + H_];
        bias.z = bi[col + 2 * H_] + bh[col + 2 * H_];
        bias.w = bi[col + 3 * H_] + bh[col + 3 * H_];
    }

    float creg[2];
    {
        const float* cin = layer ? c2in : c1in;
        int dup = (lane >> 3) & 1;
#pragma unroll
        for (int rp = 0; rp < 2; ++rp) {
            int row = wv * 16 + quad * 4 + rp * 2 + dup;
            creg[rp] = cin[(size_t)row * H_ + n0h + jj];
        }
    }

    floatx4 acc[NT];
    floatx4 pacc[NT];

    auto seg1 = [&](const bf16* A, int ldA, const bf16* Bb, int ldB,
                    auto nksC, int ksBase) {
        constexpr int NKS = decltype(nksC)::value;
        constexpr int CH  = NKS < 16 ? NKS : 16;
        const int arow = wv * 16 + (lane & 15);
        const bf16* a0 = A + (size_t)arow * ldA + quad * 8;
        for (int blk = 0; blk < NKS; blk += CH) {
            bf16x8 a0r[CH];
#pragma unroll
            for (int i = 0; i < CH; ++i)
                a0r[i] = *(const bf16x8*)(a0 + (blk + i) * 32);
            __builtin_amdgcn_sched_barrier(0);
#pragma unroll
            for (int i = 0; i < CH; ++i) {
                int c = (ksBase + blk + i) * 4 + quad;
#pragma unroll
                for (int t = 0; t < NT; ++t) {
                    int r = t * 16 + (lane & 15);
                    int cs = (c & ~15) | ((c ^ r) & 15);
                    bf16x8 bfr = *(const bf16x8*)(Bb + (size_t)r * ldB + (cs << 3));
                    acc[t] = __builtin_amdgcn_mfma_f32_16x16x32_bf16(a0r[i], bfr, acc[t], 0, 0, 0);
                }
            }
        }
    };

    auto segDual = [&](const bf16* A) {
        const int arow = wv * 16 + (lane & 15);
        const bf16* a0 = A + (size_t)arow * H_ + quad * 8;
        for (int blk = 0; blk < 32; blk += 16) {
            bf16x8 a0r[16];
#pragma unroll
            for (int i = 0; i < 16; ++i)
                a0r[i] = *(const bf16x8*)(a0 + (blk + i) * 32);
            __builtin_amdgcn_sched_barrier(0);
#pragma unroll
            for (int i = 0; i < 16; ++i) {
                int ig = blk + i;
                int c1 = (5 + ig) * 4 + quad;
                int cp = ig * 4 + quad;
#pragma unroll
                for (int t = 0; t < NT; ++t) {
                    int r = t * 16 + (lane & 15);
                    int cs1 = (c1 & ~15) | ((c1 ^ r) & 15);
                    bf16x8 b1 = *(const bf16x8*)(lds + (size_t)r * K1LDS + (cs1 << 3));
                    acc[t] = __builtin_amdgcn_mfma_f32_16x16x32_bf16(a0r[i], b1, acc[t], 0, 0, 0);
                    int csp = (cp & ~15) | ((cp ^ r) & 15);
                    bf16x8 bp = *(const bf16x8*)(ldsP + (size_t)r * KP + (csp << 3));
                    pacc[t] = __builtin_amdgcn_mfma_f32_16x16x32_bf16(a0r[i], bp, pacc[t], 0, 0, 0);
                }
            }
        }
    };

    auto epilogue = [&](bf16* hw) {
        const int base = lane & 48;
#pragma unroll
        for (int r = 0; r < 4; ++r) {
            float vi = __shfl(acc[0][r], base + jj, 64);
            float vf = __shfl(acc[0][r], base + 8 + jj, 64);
            float vg = __shfl(acc[1][r], base + jj, 64);
            float vo = __shfl(acc[1][r], base + 8 + jj, 64);
            bool cond = (((lane >> 3) & 1) == (r & 1));
            int slot = r >> 1;
            if (cond) {
                float cv = creg[slot];
                float cn = sigmoidf_(vf + bias.y) * cv
                         + sigmoidf_(vi + bias.x) * tanhf(vg + bias.z);
                creg[slot] = cn;
                float hn = sigmoidf_(vo + bias.w) * tanhf(cn);
                hst[wv][quad * 4 + r][jj] = (bf16)hn;
            }
        }
        __syncthreads();
        if (lane < 32) {
            int row_l = lane >> 1, cg = lane & 1;
            ull v = *(const ull*)&hst[wv][row_l][cg * 4];
            __hip_atomic_store((ull*)(hw + (size_t)(wv * 16 + row_l) * H_ + n0h + cg * 4),
                               v, __ATOMIC_RELAXED, __HIP_MEMORY_SCOPE_AGENT);
        }
    };

    if (layer == 0) {
#pragma unroll
        for (int t = 0; t < NT; ++t) {
            acc[t]  = (floatx4){0.f, 0.f, 0.f, 0.f};
            pacc[t] = (floatx4){0.f, 0.f, 0.f, 0.f};
        }
        seg1(xb, KX_, lds, K1LDS, IC<5>{}, 0);
    }

    for (int e = 0; e <= T_ + 1; ++e) {
        const int pm  = e % 3;
        const int pmr = (e + 2) % 3;
        float* const pbuf[3] = { p0, p1, p2 };

        if (layer == 0 && e <= T_) {
            const bf16* h1r = (e & 1) ? h1b1 : h1b0;
            segDual(h1r);

            float* pw = pbuf[pm] + (size_t)slice * B_ * NCOLS;
#pragma unroll
            for (int t = 0; t < NT; ++t)
#pragma unroll
                for (int r = 0; r < 4; ++r) {
                    int row = wv * 16 + quad * 4 + r;
                    __hip_atomic_store(pw + (size_t)row * NCOLS + t * 16 + (lane & 15),
                                       pacc[t][r], __ATOMIC_RELAXED, __HIP_MEMORY_SCOPE_AGENT);
                }

            if (e < T_) {
                bf16* hw = (e & 1) ? h1b0 : h1b1;
                epilogue(hw);
            }
        } else if (layer == 1 && e >= 2) {
#pragma unroll
            for (int t = 0; t < NT; ++t) acc[t] = (floatx4){0.f, 0.f, 0.f, 0.f};

            const float* pr = pbuf[pmr] + (size_t)slice * B_ * NCOLS;
            float pv[NT][4];
#pragma unroll
            for (int t = 0; t < NT; ++t)
#pragma unroll
                for (int r = 0; r < 4; ++r) {
                    int row = wv * 16 + quad * 4 + r;
                    pv[t][r] = pr[(size_t)row * NCOLS + t * 16 + (lane & 15)];
                }

            const bf16* h2r = (e & 1) ? h2b1 : h2b0;
            seg1(h2r, H_, lds, KP, IC<32>{}, 0);

#pragma unroll
            for (int t = 0; t < NT; ++t)
#pragma unroll
                for (int r = 0; r < 4; ++r) acc[t][r] += pv[t][r];

            bf16* hw = (e & 1) ? h2b0 : h2b1;
            epilogue(hw);
        }

        asm volatile("s_waitcnt vmcnt(0)" ::: "memory");
        __syncthreads();
        const int etag = e + 1;
        if (tid == 0)
            __hip_atomic_fetch_add(cnt + line * CSTRIDE, 1u,
                                   __ATOMIC_RELAXED, __HIP_MEMORY_SCOPE_AGENT);
        if (layer == 0 && e < T_) {
#pragma unroll
            for (int t = 0; t < NT; ++t) {
                acc[t]  = (floatx4){0.f, 0.f, 0.f, 0.f};
                pacc[t] = (floatx4){0.f, 0.f, 0.f, 0.f};
            }
            if (e + 1 < T_)
                seg1(xb + (size_t)(e + 1) * B_ * KX_, KX_, lds, K1LDS, IC<5>{}, 0);
        }
        if (layer == 0) {
            if (bid == 0) {
                if (tid < 16) {
                    const unsigned tgt = 8u * (unsigned)etag;
                    const unsigned* cp = cnt + tid * CSTRIDE;
                    while (__hip_atomic_load(cp, __ATOMIC_RELAXED, __HIP_MEMORY_SCOPE_AGENT) < tgt)
                        __builtin_amdgcn_s_sleep(1);
                }
                if (tid == 0)
                    __hip_atomic_store(cnt + L0FLAG * CSTRIDE, (unsigned)etag,
                                       __ATOMIC_RELAXED, __HIP_MEMORY_SCOPE_AGENT);
            } else if (tid == 0) {
                const unsigned* fp = cnt + L0FLAG * CSTRIDE;
                while (__hip_atomic_load(fp, __ATOMIC_RELAXED, __HIP_MEMORY_SCOPE_AGENT) < (unsigned)etag)
                    __builtin_amdgcn_s_sleep(1);
            }
            if (tid == 0 && etag >= 3) {
                const unsigned* fp = cnt + L1FLAG * CSTRIDE;
                while (__hip_atomic_load(fp, __ATOMIC_RELAXED, __HIP_MEMORY_SCOPE_AGENT) < (unsigned)(etag - 2))
                    __builtin_amdgcn_s_sleep(1);
            }
        } else {
            if (bid == 8) {
                if (tid < 16) {
                    const unsigned tgt = 8u * (unsigned)etag;
                    const unsigned* cp = cnt + (16 + tid) * CSTRIDE;
                    while (__hip_atomic_load(cp, __ATOMIC_RELAXED, __HIP_MEMORY_SCOPE_AGENT) < tgt)
                        __builtin_amdgcn_s_sleep(1);
                }
                if (tid == 0)
                    __hip_atomic_store(cnt + L1FLAG * CSTRIDE, (unsigned)etag,
                                       __ATOMIC_RELAXED, __HIP_MEMORY_SCOPE_AGENT);
            } else if (tid == 0) {
                const unsigned* fp = cnt + L1FLAG * CSTRIDE;
                while (__hip_atomic_load(fp, __ATOMIC_RELAXED, __HIP_MEMORY_SCOPE_AGENT) < (unsigned)etag)
                    __builtin_amdgcn_s_sleep(1);
            }
            if (tid == 0) {
                const unsigned* fp = cnt + L0FLAG * CSTRIDE;
                while (__hip_atomic_load(fp, __ATOMIC_RELAXED, __HIP_MEMORY_SCOPE_AGENT) < (unsigned)etag)
                    __builtin_amdgcn_s_sleep(1);
            }
        }
        __syncthreads();
        if (tid < 64)
            __builtin_amdgcn_fence(__ATOMIC_ACQUIRE, "agent");
        __syncthreads();
    }

    if (tid == 0 && layer == 0) {
        const unsigned* fp = cnt + L1FLAG * CSTRIDE;
        while (__hip_atomic_load(fp, __ATOMIC_RELAXED, __HIP_MEMORY_SCOPE_AGENT) < (unsigned)(T_ + 2))
            __builtin_amdgcn_s_sleep(1);
    }
    __syncthreads();
    if (tid < 64)
        __builtin_amdgcn_fence(__ATOMIC_ACQUIRE, "agent");
    __syncthreads();

    if (bid < B_) {
        const bf16* h2f = h2b0;
        for (int c = wv; c < C_; c += 8) {
            float a = 0.f;
            for (int k = lane; k < H_; k += 64)
                a += (float)h2f[(size_t)bid * H_ + k] * Wfc[(size_t)c * H_ + k];
#pragma unroll
            for (int off = 32; off; off >>= 1) a += __shfl_down(a, off, 64);
            if (lane == 0) out[bid * C_ + c] = a + bfc[c];
        }
    }
}

extern "C" void kernel_launch(void* const* d_in, const int* in_sizes, int n_in,
                              void* d_out, int out_size, void* d_ws, size_t ws_size,
                              hipStream_t stream)
{
    const float* x    = (const float*)d_in[0];
    const float* h1in = (const float*)d_in[1];
    const float* c1in = (const float*)d_in[2];
    const float* h2in = (const float*)d_in[3];
    const float* c2in = (const float*)d_in[4];
    const float* Wih1 = (const float*)d_in[5];
    const float* Whh1 = (const float*)d_in[6];
    const float* bih1 = (const float*)d_in[7];
    const float* bhh1 = (const float*)d_in[8];
    const float* Wih2 = (const float*)d_in[9];
    const float* Whh2 = (const float*)d_in[10];
    const float* bih2 = (const float*)d_in[11];
    const float* bhh2 = (const float*)d_in[12];
    const float* Wfc  = (const float*)d_in[13];
    const float* bfc  = (const float*)d_in[14];
    float* out = (float*)d_out;

    const size_t szXB  = (size_t)T_ * B_ * KX_ * 2;        // 10485760
    const size_t szH   = (size_t)B_ * H_ * 2;              // 262144
    const size_t szCnt = (size_t)NLINES * CSTRIDE * 4;     // 10240
    const size_t szP   = (size_t)128 * B_ * NCOLS * 4;     // 2097152
    const size_t needDec = szXB + 4 * szH + szCnt + 3 * szP;

    char* p = (char*)d_ws;
    bf16* xb = (bf16*)p;    p += szXB;
    bf16* h1b0 = (bf16*)p;  p += szH;
    bf16* h1b1 = (bf16*)p;  p += szH;
    bf16* h2b0 = (bf16*)p;  p += szH;
    bf16* h2b1 = (bf16*)p;  p += szH;
    unsigned* cnt = (unsigned*)p;  p += szCnt;
    float* p0 = (float*)p;  p += szP;
    float* p1 = (float*)p;  p += szP;
    float* p2 = (float*)p;

    const size_t citems = (size_t)T_ * B_ * KX_ + 2 * (size_t)B_ * H_ + NLINES * CSTRIDE;
    convert_all<<<(int)((citems + 255) / 256), 256, 0, stream>>>(
        x, h1in, h2in, xb, h1b0, h2b0, cnt);

    int nblk = 256;
    void* args[] = { &xb, &h1b0, &h1b1, &h2b0, &h2b1, &p0, &p1, &p2,
                     (void*)&c1in, (void*)&c2in,
                     (void*)&Wih1, (void*)&Whh1, (void*)&bih1, (void*)&bhh1,
                     (void*)&Wih2, (void*)&Whh2, (void*)&bih2, (void*)&bhh2,
                     (void*)&Wfc, (void*)&bfc, &out, &cnt, &nblk };

    const unsigned ldsRebal = (unsigned)(32 * K1LDS + 32 * KP) * 2u;  // 147456
    hipError_t err = hipErrorOutOfMemory;
    if (ws_size >= needDec) {
        if (hipFuncSetAttribute((const void*)rnn_dist8,
                                hipFuncAttributeMaxDynamicSharedMemorySize,
                                (int)ldsRebal) == hipSuccess) {
            err = hipLaunchCooperativeKernel((const void*)rnn_dist8,
                                             dim3(256), dim3(512), args,
                                             ldsRebal, stream);
        }
    }
    if (err != hipSuccess && ws_size >= needDec) {
        (void)hipGetLastError();
        if (hipFuncSetAttribute((const void*)rnn_decoup8,
                                hipFuncAttributeMaxDynamicSharedMemorySize,
                                (int)ldsRebal) == hipSuccess) {
            (void)hipLaunchCooperativeKernel((const void*)rnn_decoup8,
                                             dim3(256), dim3(512), args,
                                             ldsRebal, stream);
        }
    }
}

// Round 12
// 3101.907 us; speedup vs baseline: 1.5682x; 1.0733x over previous
//
#include <hip/hip_runtime.h>
#include <math.h>

// stacked_rnn R18: R16 (decoupled aggregator barriers, 3330us proven) +
// (1) p in PACKED BF16 (u32={t0,t1}/lane): halves the largest communicated
//     LLC stream (4->2MB/epoch) and halves p store/load instruction count.
// (2) fast transcendentals in the epilogue: sigma(x)=rcp(1+__expf(-x))
//     (inf-safe), tanh via |x|+copysign (overflow-safe) — replaces library
//     expf/tanhf slow paths on the serial epilogue chain.
// R17 post-mortem: distributed detect neutral (as was R13's arrive tweak) ->
// barrier internals exonerated; remaining cost is per-epoch dataflow.
// Fallback = R16 primary VERBATIM (f32 p, library math); ws carve keeps
// f32-sized p buffers so both kernels are launchable.

typedef __bf16 bf16;
typedef __bf16 bf16x8 __attribute__((ext_vector_type(8)));
typedef float floatx4 __attribute__((ext_vector_type(4)));
typedef unsigned long long ull;

#define B_   128
#define T_   256
#define H_   1024
#define I_   150
#define KX_  160
#define C_   60
#define K1LDS 1280   // L0 W1 LDS row width in elems (x 160 + h1 1024 + pad)
#define KP    1024   // Wih2 / Whh2 LDS row width
#define NLINES 40    // zeroed counter lines (0..31 arrivals, 32/33 flags)
#define CSTRIDE 64   // uints between lines (256B)
#define L0FLAG 32
#define L1FLAG 33
#define NCOLS 32     // gate-cols per block tile
#define NHC  8       // h-cols per block (NCOLS/4)
#define NT   2       // N-tiles of 16

template<int N> struct IC { static constexpr int value = N; };

__device__ __forceinline__ float sigmoidf_(float x) { return 1.f / (1.f + expf(-x)); }

// fast inf-safe sigmoid: rcp(1+e^-x); e^-x->inf => rcp(inf)=0 (no NaN)
__device__ __forceinline__ float fsig(float x) {
    return __builtin_amdgcn_rcpf(1.f + __expf(-x));
}
// fast overflow-safe tanh: t=e^{-2|x|} in (0,1]; tanh=|sign|*(1-t)/(1+t)
__device__ __forceinline__ float ftanh(float x) {
    float t = __expf(-2.f * fabsf(x));
    float r = (1.f - t) * __builtin_amdgcn_rcpf(1.f + t);
    return copysignf(r, x);
}

// ---------------- conversion / init kernel ----------------
__global__ __launch_bounds__(256)
void convert_all(const float* __restrict__ x,
                 const float* __restrict__ h1in, const float* __restrict__ h2in,
                 bf16* __restrict__ xb, bf16* __restrict__ h1b0, bf16* __restrict__ h2b0,
                 unsigned* __restrict__ cnt)
{
    const size_t nXB = (size_t)T_ * B_ * KX_;   // 5242880
    const size_t nHC = (size_t)B_ * H_;         // 131072
    size_t idx = (size_t)blockIdx.x * 256 + threadIdx.x;

    if (idx < nXB) {                            // x [B][T][150] -> xb [T][B][160]
        size_t t = idx / (B_ * KX_);
        size_t r = idx - t * (B_ * KX_);
        size_t b = r / KX_, k = r - b * KX_;
        xb[idx] = (k < I_) ? (bf16)x[(b * T_ + t) * I_ + k] : (bf16)0.f;
        return;
    }
    idx -= nXB;
    if (idx < nHC) { h1b0[idx] = (bf16)h1in[idx]; return; }
    idx -= nHC;
    if (idx < nHC) { h2b0[idx] = (bf16)h2in[idx]; return; }
    idx -= nHC;
    if (idx < NLINES * CSTRIDE) cnt[idx] = 0u;
}

// ---- shared staging helper (both persistent kernels, 512 threads) ----
__device__ __forceinline__ void stage_rebal(
    bf16* lds, bf16* ldsP, int tid, int layer, int n0h,
    const float* Wih1, const float* Whh1, const float* Wih2, const float* Whh2)
{
    if (layer == 0) {
        {   // W1 region: 32 rows x K1LDS (x [0,160), h1 [160,1184), pad)
            const int cpr = K1LDS >> 3;           // 160
            const int total = NCOLS * cpr;
            for (int ci = tid; ci < total; ci += 512) {
                int r = ci / cpr, c = ci - r * cpr;
                int g = r / NHC, j = r - g * NHC;
                int grow = (g << 10) + n0h + j;
                int k0 = c << 3;
                float v[8];
#pragma unroll
                for (int u = 0; u < 8; ++u) {
                    int k = k0 + u;
                    v[u] = (k < I_) ? Wih1[(size_t)grow * I_ + k]
                         : (k < KX_) ? 0.f
                         : (k < KX_ + H_) ? Whh1[(size_t)grow * H_ + (k - KX_)] : 0.f;
                }
                int cs = (c & ~15) | ((c ^ r) & 15);
                bf16* dst = lds + (size_t)r * K1LDS + (cs << 3);
#pragma unroll
                for (int u = 0; u < 8; ++u) dst[u] = (bf16)v[u];
            }
        }
        {   // Wih2 region: 32 rows x KP
            const int cpr = KP >> 3;              // 128
            const int total = NCOLS * cpr;
            for (int ci = tid; ci < total; ci += 512) {
                int r = ci / cpr, c = ci - r * cpr;
                int g = r / NHC, j = r - g * NHC;
                int grow = (g << 10) + n0h + j;
                int k0 = c << 3;
                float v[8];
#pragma unroll
                for (int u = 0; u < 8; ++u) v[u] = Wih2[(size_t)grow * H_ + k0 + u];
                int cs = (c & ~15) | ((c ^ r) & 15);
                bf16* dst = ldsP + (size_t)r * KP + (cs << 3);
#pragma unroll
                for (int u = 0; u < 8; ++u) dst[u] = (bf16)v[u];
            }
        }
    } else {
        // Whh2 region: 32 rows x KP
        const int cpr = KP >> 3;
        const int total = NCOLS * cpr;
        for (int ci = tid; ci < total; ci += 512) {
            int r = ci / cpr, c = ci - r * cpr;
            int g = r / NHC, j = r - g * NHC;
            int grow = (g << 10) + n0h + j;
            int k0 = c << 3;
            float v[8];
#pragma unroll
            for (int u = 0; u < 8; ++u) v[u] = Whh2[(size_t)grow * H_ + k0 + u];
            int cs = (c & ~15) | ((c ^ r) & 15);
            bf16* dst = lds + (size_t)r * KP + (cs << 3);
#pragma unroll
            for (int u = 0; u < 8; ++u) dst[u] = (bf16)v[u];
        }
    }
}

// ================= R18 primary: bf16-p + fast-math decoupled kernel =========
// Structure identical to R16 primary (aggregator decoupled barriers, p
// triple-buffered write e%3 / read (e+2)%3). p stored as u32 {bf16 t0, t1}:
// writer packs pacc[0][r],pacc[1][r]; reader at same (row, lane&15) unpacks.
__global__ __launch_bounds__(512, 2)
void rnn_bf16p8(const bf16* __restrict__ xb,
                bf16* __restrict__ h1b0, bf16* __restrict__ h1b1,
                bf16* __restrict__ h2b0, bf16* __restrict__ h2b1,
                float* __restrict__ p0, float* __restrict__ p1, float* __restrict__ p2,
                const float* __restrict__ c1in, const float* __restrict__ c2in,
                const float* __restrict__ Wih1, const float* __restrict__ Whh1,
                const float* __restrict__ bih1, const float* __restrict__ bhh1,
                const float* __restrict__ Wih2, const float* __restrict__ Whh2,
                const float* __restrict__ bih2, const float* __restrict__ bhh2,
                const float* __restrict__ Wfc, const float* __restrict__ bfc,
                float* __restrict__ out, unsigned* __restrict__ cnt, int nblk)
{
    extern __shared__ bf16 lds[];
    __shared__ __align__(16) bf16 hst[8][16][NHC];   // epilogue staging

    const int tid   = threadIdx.x;
    const int bid   = blockIdx.x;
    const int layer = (bid >> 3) & 1;
    const int slice = (bid & 7) | ((bid >> 4) << 3);
    const int n0h   = slice * NHC;
    const int line  = layer * 16 + ((bid & 7) | (((bid >> 4) & 1) << 3));
    bf16* ldsP = lds + 32 * K1LDS;               // L0's Wih2 region

    stage_rebal(lds, ldsP, tid, layer, n0h, Wih1, Whh1, Wih2, Whh2);
    __syncthreads();

    const int lane = tid & 63;
    const int wv   = tid >> 6;          // 0..7
    const int jj   = lane & (NHC - 1);
    const int quad = lane >> 4;

    float4 bias;
    {
        const float* bi = layer ? bih2 : bih1;
        const float* bh = layer ? bhh2 : bhh1;
        int col = n0h + jj;
        bias.x = bi[col] + bh[col];
        bias.y = bi[col + H_] + bh[col + H_];
        bias.z = bi[col + 2 * H_] + bh[col + 2 * H_];
        bias.w = bi[col + 3 * H_] + bh[col + 3 * H_];
    }

    float creg[2];
    {
        const float* cin = layer ? c2in : c1in;
        int dup = (lane >> 3) & 1;
#pragma unroll
        for (int rp = 0; rp < 2; ++rp) {
            int row = wv * 16 + quad * 4 + rp * 2 + dup;
            creg[rp] = cin[(size_t)row * H_ + n0h + jj];
        }
    }

    floatx4 acc[NT];
    floatx4 pacc[NT];

    // generic single-target K-segment (CH=16, proven)
    auto seg1 = [&](const bf16* A, int ldA, const bf16* Bb, int ldB,
                    auto nksC, int ksBase) {
        constexpr int NKS = decltype(nksC)::value;
        constexpr int CH  = NKS < 16 ? NKS : 16;
        const int arow = wv * 16 + (lane & 15);
        const bf16* a0 = A + (size_t)arow * ldA + quad * 8;
        for (int blk = 0; blk < NKS; blk += CH) {
            bf16x8 a0r[CH];
#pragma unroll
            for (int i = 0; i < CH; ++i)
                a0r[i] = *(const bf16x8*)(a0 + (blk + i) * 32);
            __builtin_amdgcn_sched_barrier(0);
#pragma unroll
            for (int i = 0; i < CH; ++i) {
                int c = (ksBase + blk + i) * 4 + quad;
#pragma unroll
                for (int t = 0; t < NT; ++t) {
                    int r = t * 16 + (lane & 15);
                    int cs = (c & ~15) | ((c ^ r) & 15);
                    bf16x8 bfr = *(const bf16x8*)(Bb + (size_t)r * ldB + (cs << 3));
                    acc[t] = __builtin_amdgcn_mfma_f32_16x16x32_bf16(a0r[i], bfr, acc[t], 0, 0, 0);
                }
            }
        }
    };

    // dual-target h1-segment (L0): gates1 into acc (W1, ksBase 5) AND
    // p into pacc (Wih2, ksBase 0) from the SAME A stream.
    auto segDual = [&](const bf16* A) {
        const int arow = wv * 16 + (lane & 15);
        const bf16* a0 = A + (size_t)arow * H_ + quad * 8;
        for (int blk = 0; blk < 32; blk += 16) {
            bf16x8 a0r[16];
#pragma unroll
            for (int i = 0; i < 16; ++i)
                a0r[i] = *(const bf16x8*)(a0 + (blk + i) * 32);
            __builtin_amdgcn_sched_barrier(0);
#pragma unroll
            for (int i = 0; i < 16; ++i) {
                int ig = blk + i;
                int c1 = (5 + ig) * 4 + quad;
                int cp = ig * 4 + quad;
#pragma unroll
                for (int t = 0; t < NT; ++t) {
                    int r = t * 16 + (lane & 15);
                    int cs1 = (c1 & ~15) | ((c1 ^ r) & 15);
                    bf16x8 b1 = *(const bf16x8*)(lds + (size_t)r * K1LDS + (cs1 << 3));
                    acc[t] = __builtin_amdgcn_mfma_f32_16x16x32_bf16(a0r[i], b1, acc[t], 0, 0, 0);
                    int csp = (cp & ~15) | ((cp ^ r) & 15);
                    bf16x8 bp = *(const bf16x8*)(ldsP + (size_t)r * KP + (csp << 3));
                    pacc[t] = __builtin_amdgcn_mfma_f32_16x16x32_bf16(a0r[i], bp, pacc[t], 0, 0, 0);
                }
            }
        }
    };

    // epilogue: shfl-gather gates, update creg (fast math), stage h, store h
    auto epilogue = [&](bf16* hw) {
        const int base = lane & 48;
#pragma unroll
        for (int r = 0; r < 4; ++r) {
            float vi = __shfl(acc[0][r], base + jj, 64);
            float vf = __shfl(acc[0][r], base + 8 + jj, 64);
            float vg = __shfl(acc[1][r], base + jj, 64);
            float vo = __shfl(acc[1][r], base + 8 + jj, 64);
            bool cond = (((lane >> 3) & 1) == (r & 1));
            int slot = r >> 1;
            if (cond) {
                float cv = creg[slot];
                float cn = fsig(vf + bias.y) * cv
                         + fsig(vi + bias.x) * ftanh(vg + bias.z);
                creg[slot] = cn;
                float hn = fsig(vo + bias.w) * ftanh(cn);
                hst[wv][quad * 4 + r][jj] = (bf16)hn;
            }
        }
        __syncthreads();
        if (lane < 32) {
            int row_l = lane >> 1, cg = lane & 1;
            ull v = *(const ull*)&hst[wv][row_l][cg * 4];
            __hip_atomic_store((ull*)(hw + (size_t)(wv * 16 + row_l) * H_ + n0h + cg * 4),
                               v, __ATOMIC_RELAXED, __HIP_MEMORY_SCOPE_AGENT);
        }
    };

    // prologue (L0): zero accs and pre-compute x(0) contribution
    if (layer == 0) {
#pragma unroll
        for (int t = 0; t < NT; ++t) {
            acc[t]  = (floatx4){0.f, 0.f, 0.f, 0.f};
            pacc[t] = (floatx4){0.f, 0.f, 0.f, 0.f};
        }
        seg1(xb, KX_, lds, K1LDS, IC<5>{}, 0);     // x(0)
    }

    for (int e = 0; e <= T_ + 1; ++e) {
        const int pm  = e % 3;            // p(e) write buffer
        const int pmr = (e + 2) % 3;      // p(e-1) read buffer
        float* const pbuf[3] = { p0, p1, p2 };

        if (layer == 0 && e <= T_) {
            // acc holds x(e) part (preloaded); dual-seg adds h1(e) part + p(e)
            const bf16* h1r = (e & 1) ? h1b1 : h1b0;          // h1^(e)
            segDual(h1r);

            // publish p(e) slice: packed bf16 u32 {t0,t1} per (row, lane&15)
            unsigned* pw = (unsigned*)pbuf[pm] + (size_t)slice * B_ * 16;
#pragma unroll
            for (int r = 0; r < 4; ++r) {
                int row = wv * 16 + quad * 4 + r;
                bf16 b0 = (bf16)pacc[0][r];
                bf16 b1 = (bf16)pacc[1][r];
                unsigned u = (unsigned)(*(unsigned short*)&b0)
                           | ((unsigned)(*(unsigned short*)&b1) << 16);
                __hip_atomic_store(pw + (size_t)row * 16 + (lane & 15), u,
                                   __ATOMIC_RELAXED, __HIP_MEMORY_SCOPE_AGENT);
            }

            if (e < T_) {
                bf16* hw = (e & 1) ? h1b0 : h1b1;              // h1^(e+1)
                epilogue(hw);
            }
        } else if (layer == 1 && e >= 2) {
#pragma unroll
            for (int t = 0; t < NT; ++t) acc[t] = (floatx4){0.f, 0.f, 0.f, 0.f};

            // prefetch p(e-1) slice (packed bf16; post-fence coherent)
            const unsigned* pr = (const unsigned*)pbuf[pmr] + (size_t)slice * B_ * 16;
            float pv[NT][4];
#pragma unroll
            for (int r = 0; r < 4; ++r) {
                int row = wv * 16 + quad * 4 + r;
                unsigned u = pr[(size_t)row * 16 + (lane & 15)];
                unsigned short s0 = (unsigned short)(u & 0xffffu);
                unsigned short s1 = (unsigned short)(u >> 16);
                pv[0][r] = (float)(*(bf16*)&s0);
                pv[1][r] = (float)(*(bf16*)&s1);
            }

            const bf16* h2r = (e & 1) ? h2b1 : h2b0;           // h2^(e-2)
            seg1(h2r, H_, lds, KP, IC<32>{}, 0);

#pragma unroll
            for (int t = 0; t < NT; ++t)
#pragma unroll
                for (int r = 0; r < 4; ++r) acc[t][r] += pv[t][r];

            bf16* hw = (e & 1) ? h2b0 : h2b1;                  // h2^(e-1)
            epilogue(hw);
        }

        // ---- decoupled group barrier (R16 proven form) ----
        asm volatile("s_waitcnt vmcnt(0)" ::: "memory");
        __syncthreads();
        const int etag = e + 1;
        if (tid == 0)
            __hip_atomic_fetch_add(cnt + line * CSTRIDE, 1u,
                                   __ATOMIC_RELAXED, __HIP_MEMORY_SCOPE_AGENT);
        // overlapped work in the barrier window (L0): next-epoch x-seg
        if (layer == 0 && e < T_) {
#pragma unroll
            for (int t = 0; t < NT; ++t) {
                acc[t]  = (floatx4){0.f, 0.f, 0.f, 0.f};
                pacc[t] = (floatx4){0.f, 0.f, 0.f, 0.f};
            }
            if (e + 1 < T_)
                seg1(xb + (size_t)(e + 1) * B_ * KX_, KX_, lds, K1LDS, IC<5>{}, 0);
        }
        if (layer == 0) {
            if (bid == 0) {
                if (tid < 16) {
                    const unsigned tgt = 8u * (unsigned)etag;
                    const unsigned* cp = cnt + tid * CSTRIDE;
                    while (__hip_atomic_load(cp, __ATOMIC_RELAXED, __HIP_MEMORY_SCOPE_AGENT) < tgt)
                        __builtin_amdgcn_s_sleep(1);
                }
                if (tid == 0)
                    __hip_atomic_store(cnt + L0FLAG * CSTRIDE, (unsigned)etag,
                                       __ATOMIC_RELAXED, __HIP_MEMORY_SCOPE_AGENT);
            } else if (tid == 0) {
                const unsigned* fp = cnt + L0FLAG * CSTRIDE;
                while (__hip_atomic_load(fp, __ATOMIC_RELAXED, __HIP_MEMORY_SCOPE_AGENT) < (unsigned)etag)
                    __builtin_amdgcn_s_sleep(1);
            }
            if (tid == 0 && etag >= 3) {   // slack-2 wait on L1 (p-buffer reuse)
                const unsigned* fp = cnt + L1FLAG * CSTRIDE;
                while (__hip_atomic_load(fp, __ATOMIC_RELAXED, __HIP_MEMORY_SCOPE_AGENT) < (unsigned)(etag - 2))
                    __builtin_amdgcn_s_sleep(1);
            }
        } else {
            if (bid == 8) {
                if (tid < 16) {
                    const unsigned tgt = 8u * (unsigned)etag;
                    const unsigned* cp = cnt + (16 + tid) * CSTRIDE;
                    while (__hip_atomic_load(cp, __ATOMIC_RELAXED, __HIP_MEMORY_SCOPE_AGENT) < tgt)
                        __builtin_amdgcn_s_sleep(1);
                }
                if (tid == 0)
                    __hip_atomic_store(cnt + L1FLAG * CSTRIDE, (unsigned)etag,
                                       __ATOMIC_RELAXED, __HIP_MEMORY_SCOPE_AGENT);
            } else if (tid == 0) {
                const unsigned* fp = cnt + L1FLAG * CSTRIDE;
                while (__hip_atomic_load(fp, __ATOMIC_RELAXED, __HIP_MEMORY_SCOPE_AGENT) < (unsigned)etag)
                    __builtin_amdgcn_s_sleep(1);
            }
            if (tid == 0) {                // zero-slack wait on L0 (p(e) ready)
                const unsigned* fp = cnt + L0FLAG * CSTRIDE;
                while (__hip_atomic_load(fp, __ATOMIC_RELAXED, __HIP_MEMORY_SCOPE_AGENT) < (unsigned)etag)
                    __builtin_amdgcn_s_sleep(1);
            }
        }
        __syncthreads();
        // acquire (cache inv) by wave 0 only
        if (tid < 64)
            __builtin_amdgcn_fence(__ATOMIC_ACQUIRE, "agent");
        __syncthreads();
    }

    // final join: everyone must see L1's last epoch (h2^(256)) before FC
    if (tid == 0 && layer == 0) {
        const unsigned* fp = cnt + L1FLAG * CSTRIDE;
        while (__hip_atomic_load(fp, __ATOMIC_RELAXED, __HIP_MEMORY_SCOPE_AGENT) < (unsigned)(T_ + 2))
            __builtin_amdgcn_s_sleep(1);
    }
    __syncthreads();
    if (tid < 64)
        __builtin_amdgcn_fence(__ATOMIC_ACQUIRE, "agent");
    __syncthreads();

    // ---- fused FC: out = h2^(256) @ Wfc^T + bfc ; h2^(256) is in h2b0 ----
    if (bid < B_) {
        const bf16* h2f = h2b0;
        for (int c = wv; c < C_; c += 8) {
            float a = 0.f;
            for (int k = lane; k < H_; k += 64)
                a += (float)h2f[(size_t)bid * H_ + k] * Wfc[(size_t)c * H_ + k];
#pragma unroll
            for (int off = 32; off; off >>= 1) a += __shfl_down(a, off, 64);
            if (lane == 0) out[bid * C_ + c] = a + bfc[c];
        }
    }
}

// ============ fallback: R16 primary VERBATIM (3330us proven, f32 p) =========
__global__ __launch_bounds__(512, 2)
void rnn_decoup8(const bf16* __restrict__ xb,
                 bf16* __restrict__ h1b0, bf16* __restrict__ h1b1,
                 bf16* __restrict__ h2b0, bf16* __restrict__ h2b1,
                 float* __restrict__ p0, float* __restrict__ p1, float* __restrict__ p2,
                 const float* __restrict__ c1in, const float* __restrict__ c2in,
                 const float* __restrict__ Wih1, const float* __restrict__ Whh1,
                 const float* __restrict__ bih1, const float* __restrict__ bhh1,
                 const float* __restrict__ Wih2, const float* __restrict__ Whh2,
                 const float* __restrict__ bih2, const float* __restrict__ bhh2,
                 const float* __restrict__ Wfc, const float* __restrict__ bfc,
                 float* __restrict__ out, unsigned* __restrict__ cnt, int nblk)
{
    extern __shared__ bf16 lds[];
    __shared__ __align__(16) bf16 hst[8][16][NHC];

    const int tid   = threadIdx.x;
    const int bid   = blockIdx.x;
    const int layer = (bid >> 3) & 1;
    const int slice = (bid & 7) | ((bid >> 4) << 3);
    const int n0h   = slice * NHC;
    const int line  = layer * 16 + ((bid & 7) | (((bid >> 4) & 1) << 3));
    bf16* ldsP = lds + 32 * K1LDS;

    stage_rebal(lds, ldsP, tid, layer, n0h, Wih1, Whh1, Wih2, Whh2);
    __syncthreads();

    const int lane = tid & 63;
    const int wv   = tid >> 6;
    const int jj   = lane & (NHC - 1);
    const int quad = lane >> 4;

    float4 bias;
    {
        const float* bi = layer ? bih2 : bih1;
        const float* bh = layer ? bhh2 : bhh1;
        int col = n0h + jj;
        bias.x = bi[col] + bh[col];
        bias.y = bi[col + H_] + bh[col + H_];
        bias.z = bi[col + 2 * H_] + bh[col + 2 * H_];
        bias.w = bi[col + 3 * H_] + bh[col + 3 * H_];
    }

    float creg[2];
    {
        const float* cin = layer ? c2in : c1in;
        int dup = (lane >> 3) & 1;
#pragma unroll
        for (int rp = 0; rp < 2; ++rp) {
            int row = wv * 16 + quad * 4 + rp * 2 + dup;
            creg[rp] = cin[(size_t)row * H_ + n0h + jj];
        }
    }

    floatx4 acc[NT];
    floatx4 pacc[NT];

    auto seg1 = [&](const bf16* A, int ldA, const bf16* Bb, int ldB,
                    auto nksC, int ksBase) {
        constexpr int NKS = decltype(nksC)::value;
        constexpr int CH  = NKS < 16 ? NKS : 16;
        const int arow = wv * 16 + (lane & 15);
        const bf16* a0 = A + (size_t)arow * ldA + quad * 8;
        for (int blk = 0; blk < NKS; blk += CH) {
            bf16x8 a0r[CH];
#pragma unroll
            for (int i = 0; i < CH; ++i)
                a0r[i] = *(const bf16x8*)(a0 + (blk + i) * 32);
            __builtin_amdgcn_sched_barrier(0);
#pragma unroll
            for (int i = 0; i < CH; ++i) {
                int c = (ksBase + blk + i) * 4 + quad;
#pragma unroll
                for (int t = 0; t < NT; ++t) {
                    int r = t * 16 + (lane & 15);
                    int cs = (c & ~15) | ((c ^ r) & 15);
                    bf16x8 bfr = *(const bf16x8*)(Bb + (size_t)r * ldB + (cs << 3));
                    acc[t] = __builtin_amdgcn_mfma_f32_16x16x32_bf16(a0r[i], bfr, acc[t], 0, 0, 0);
                }
            }
        }
    };

    auto segDual = [&](const bf16* A) {
        const int arow = wv * 16 + (lane & 15);
        const bf16* a0 = A + (size_t)arow * H_ + quad * 8;
        for (int blk = 0; blk < 32; blk += 16) {
            bf16x8 a0r[16];
#pragma unroll
            for (int i = 0; i < 16; ++i)
                a0r[i] = *(const bf16x8*)(a0 + (blk + i) * 32);
            __builtin_amdgcn_sched_barrier(0);
#pragma unroll
            for (int i = 0; i < 16; ++i) {
                int ig = blk + i;
                int c1 = (5 + ig) * 4 + quad;
                int cp = ig * 4 + quad;
#pragma unroll
                for (int t = 0; t < NT; ++t) {
                    int r = t * 16 + (lane & 15);
                    int cs1 = (c1 & ~15) | ((c1 ^ r) & 15);
                    bf16x8 b1 = *(const bf16x8*)(lds + (size_t)r * K1LDS + (cs1 << 3));
                    acc[t] = __builtin_amdgcn_mfma_f32_16x16x32_bf16(a0r[i], b1, acc[t], 0, 0, 0);
                    int csp = (cp & ~15) | ((cp ^ r) & 15);
                    bf16x8 bp = *(const bf16x8*)(ldsP + (size_t)r * KP + (csp << 3));
                    pacc[t] = __builtin_amdgcn_mfma_f32_16x16x32_bf16(a0r[i], bp, pacc[t], 0, 0, 0);
                }
            }
        }
    };

    auto epilogue = [&](bf16* hw) {
        const int base = lane & 48;
#pragma unroll
        for (int r = 0; r < 4; ++r) {
            float vi = __shfl(acc[0][r], base + jj, 64);
            float vf = __shfl(acc[0][r], base + 8 + jj, 64);
            float vg = __shfl(acc[1][r], base + jj, 64);
            float vo = __shfl(acc[1][r], base + 8 + jj, 64);
            bool cond = (((lane >> 3) & 1) == (r & 1));
            int slot = r >> 1;
            if (cond) {
                float cv = creg[slot];
                float cn = sigmoidf_(vf + bias.y) * cv
                         + sigmoidf_(vi + bias.x) * tanhf(vg + bias.z);
                creg[slot] = cn;
                float hn = sigmoidf_(vo + bias.w) * tanhf(cn);
                hst[wv][quad * 4 + r][jj] = (bf16)hn;
            }
        }
        __syncthreads();
        if (lane < 32) {
            int row_l = lane >> 1, cg = lane & 1;
            ull v = *(const ull*)&hst[wv][row_l][cg * 4];
            __hip_atomic_store((ull*)(hw + (size_t)(wv * 16 + row_l) * H_ + n0h + cg * 4),
                               v, __ATOMIC_RELAXED, __HIP_MEMORY_SCOPE_AGENT);
        }
    };

    if (layer == 0) {
#pragma unroll
        for (int t = 0; t < NT; ++t) {
            acc[t]  = (floatx4){0.f, 0.f, 0.f, 0.f};
            pacc[t] = (floatx4){0.f, 0.f, 0.f, 0.f};
        }
        seg1(xb, KX_, lds, K1LDS, IC<5>{}, 0);
    }

    for (int e = 0; e <= T_ + 1; ++e) {
        const int pm  = e % 3;
        const int pmr = (e + 2) % 3;
        float* const pbuf[3] = { p0, p1, p2 };

        if (layer == 0 && e <= T_) {
            const bf16* h1r = (e & 1) ? h1b1 : h1b0;
            segDual(h1r);

            float* pw = pbuf[pm] + (size_t)slice * B_ * NCOLS;
#pragma unroll
            for (int t = 0; t < NT; ++t)
#pragma unroll
                for (int r = 0; r < 4; ++r) {
                    int row = wv * 16 + quad * 4 + r;
                    __hip_atomic_store(pw + (size_t)row * NCOLS + t * 16 + (lane & 15),
                                       pacc[t][r], __ATOMIC_RELAXED, __HIP_MEMORY_SCOPE_AGENT);
                }

            if (e < T_) {
                bf16* hw = (e & 1) ? h1b0 : h1b1;
                epilogue(hw);
            }
        } else if (layer == 1 && e >= 2) {
#pragma unroll
            for (int t = 0; t < NT; ++t) acc[t] = (floatx4){0.f, 0.f, 0.f, 0.f};

            const float* pr = pbuf[pmr] + (size_t)slice * B_ * NCOLS;
            float pv[NT][4];
#pragma unroll
            for (int t = 0; t < NT; ++t)
#pragma unroll
                for (int r = 0; r < 4; ++r) {
                    int row = wv * 16 + quad * 4 + r;
                    pv[t][r] = pr[(size_t)row * NCOLS + t * 16 + (lane & 15)];
                }

            const bf16* h2r = (e & 1) ? h2b1 : h2b0;
            seg1(h2r, H_, lds, KP, IC<32>{}, 0);

#pragma unroll
            for (int t = 0; t < NT; ++t)
#pragma unroll
                for (int r = 0; r < 4; ++r) acc[t][r] += pv[t][r];

            bf16* hw = (e & 1) ? h2b0 : h2b1;
            epilogue(hw);
        }

        asm volatile("s_waitcnt vmcnt(0)" ::: "memory");
        __syncthreads();
        const int etag = e + 1;
        if (tid == 0)
            __hip_atomic_fetch_add(cnt + line * CSTRIDE, 1u,
                                   __ATOMIC_RELAXED, __HIP_MEMORY_SCOPE_AGENT);
        if (layer == 0 && e < T_) {
#pragma unroll
            for (int t = 0; t < NT; ++t) {
                acc[t]  = (floatx4){0.f, 0.f, 0.f, 0.f};
                pacc[t] = (floatx4){0.f, 0.f, 0.f, 0.f};
            }
            if (e + 1 < T_)
                seg1(xb + (size_t)(e + 1) * B_ * KX_, KX_, lds, K1LDS, IC<5>{}, 0);
        }
        if (layer == 0) {
            if (bid == 0) {
                if (tid < 16) {
                    const unsigned tgt = 8u * (unsigned)etag;
                    const unsigned* cp = cnt + tid * CSTRIDE;
                    while (__hip_atomic_load(cp, __ATOMIC_RELAXED, __HIP_MEMORY_SCOPE_AGENT) < tgt)
                        __builtin_amdgcn_s_sleep(1);
                }
                if (tid == 0)
                    __hip_atomic_store(cnt + L0FLAG * CSTRIDE, (unsigned)etag,
                                       __ATOMIC_RELAXED, __HIP_MEMORY_SCOPE_AGENT);
            } else if (tid == 0) {
                const unsigned* fp = cnt + L0FLAG * CSTRIDE;
                while (__hip_atomic_load(fp, __ATOMIC_RELAXED, __HIP_MEMORY_SCOPE_AGENT) < (unsigned)etag)
                    __builtin_amdgcn_s_sleep(1);
            }
            if (tid == 0 && etag >= 3) {
                const unsigned* fp = cnt + L1FLAG * CSTRIDE;
                while (__hip_atomic_load(fp, __ATOMIC_RELAXED, __HIP_MEMORY_SCOPE_AGENT) < (unsigned)(etag - 2))
                    __builtin_amdgcn_s_sleep(1);
            }
        } else {
            if (bid == 8) {
                if (tid < 16) {
                    const unsigned tgt = 8u * (unsigned)etag;
                    const unsigned* cp = cnt + (16 + tid) * CSTRIDE;
                    while (__hip_atomic_load(cp, __ATOMIC_RELAXED, __HIP_MEMORY_SCOPE_AGENT) < tgt)
                        __builtin_amdgcn_s_sleep(1);
                }
                if (tid == 0)
                    __hip_atomic_store(cnt + L1FLAG * CSTRIDE, (unsigned)etag,
                                       __ATOMIC_RELAXED, __HIP_MEMORY_SCOPE_AGENT);
            } else if (tid == 0) {
                const unsigned* fp = cnt + L1FLAG * CSTRIDE;
                while (__hip_atomic_load(fp, __ATOMIC_RELAXED, __HIP_MEMORY_SCOPE_AGENT) < (unsigned)etag)
                    __builtin_amdgcn_s_sleep(1);
            }
            if (tid == 0) {
                const unsigned* fp = cnt + L0FLAG * CSTRIDE;
                while (__hip_atomic_load(fp, __ATOMIC_RELAXED, __HIP_MEMORY_SCOPE_AGENT) < (unsigned)etag)
                    __builtin_amdgcn_s_sleep(1);
            }
        }
        __syncthreads();
        if (tid < 64)
            __builtin_amdgcn_fence(__ATOMIC_ACQUIRE, "agent");
        __syncthreads();
    }

    if (tid == 0 && layer == 0) {
        const unsigned* fp = cnt + L1FLAG * CSTRIDE;
        while (__hip_atomic_load(fp, __ATOMIC_RELAXED, __HIP_MEMORY_SCOPE_AGENT) < (unsigned)(T_ + 2))
            __builtin_amdgcn_s_sleep(1);
    }
    __syncthreads();
    if (tid < 64)
        __builtin_amdgcn_fence(__ATOMIC_ACQUIRE, "agent");
    __syncthreads();

    if (bid < B_) {
        const bf16* h2f = h2b0;
        for (int c = wv; c < C_; c += 8) {
            float a = 0.f;
            for (int k = lane; k < H_; k += 64)
                a += (float)h2f[(size_t)bid * H_ + k] * Wfc[(size_t)c * H_ + k];
#pragma unroll
            for (int off = 32; off; off >>= 1) a += __shfl_down(a, off, 64);
            if (lane == 0) out[bid * C_ + c] = a + bfc[c];
        }
    }
}

extern "C" void kernel_launch(void* const* d_in, const int* in_sizes, int n_in,
                              void* d_out, int out_size, void* d_ws, size_t ws_size,
                              hipStream_t stream)
{
    const float* x    = (const float*)d_in[0];
    const float* h1in = (const float*)d_in[1];
    const float* c1in = (const float*)d_in[2];
    const float* h2in = (const float*)d_in[3];
    const float* c2in = (const float*)d_in[4];
    const float* Wih1 = (const float*)d_in[5];
    const float* Whh1 = (const float*)d_in[6];
    const float* bih1 = (const float*)d_in[7];
    const float* bhh1 = (const float*)d_in[8];
    const float* Wih2 = (const float*)d_in[9];
    const float* Whh2 = (const float*)d_in[10];
    const float* bih2 = (const float*)d_in[11];
    const float* bhh2 = (const float*)d_in[12];
    const float* Wfc  = (const float*)d_in[13];
    const float* bfc  = (const float*)d_in[14];
    float* out = (float*)d_out;

    // ws carve: p buffers sized for the f32 fallback (superset of bf16 primary)
    const size_t szXB  = (size_t)T_ * B_ * KX_ * 2;        // 10485760
    const size_t szH   = (size_t)B_ * H_ * 2;              // 262144
    const size_t szCnt = (size_t)NLINES * CSTRIDE * 4;     // 10240
    const size_t szP   = (size_t)128 * B_ * NCOLS * 4;     // 2097152 (f32 sizing)
    const size_t needDec = szXB + 4 * szH + szCnt + 3 * szP;

    char* p = (char*)d_ws;
    bf16* xb = (bf16*)p;    p += szXB;
    bf16* h1b0 = (bf16*)p;  p += szH;
    bf16* h1b1 = (bf16*)p;  p += szH;
    bf16* h2b0 = (bf16*)p;  p += szH;
    bf16* h2b1 = (bf16*)p;  p += szH;
    unsigned* cnt = (unsigned*)p;  p += szCnt;
    float* p0 = (float*)p;  p += szP;
    float* p1 = (float*)p;  p += szP;
    float* p2 = (float*)p;

    const size_t citems = (size_t)T_ * B_ * KX_ + 2 * (size_t)B_ * H_ + NLINES * CSTRIDE;
    convert_all<<<(int)((citems + 255) / 256), 256, 0, stream>>>(
        x, h1in, h2in, xb, h1b0, h2b0, cnt);

    int nblk = 256;
    void* args[] = { &xb, &h1b0, &h1b1, &h2b0, &h2b1, &p0, &p1, &p2,
                     (void*)&c1in, (void*)&c2in,
                     (void*)&Wih1, (void*)&Whh1, (void*)&bih1, (void*)&bhh1,
                     (void*)&Wih2, (void*)&Whh2, (void*)&bih2, (void*)&bhh2,
                     (void*)&Wfc, (void*)&bfc, &out, &cnt, &nblk };

    const unsigned ldsRebal = (unsigned)(32 * K1LDS + 32 * KP) * 2u;  // 147456
    hipError_t err = hipErrorOutOfMemory;
    if (ws_size >= needDec) {
        if (hipFuncSetAttribute((const void*)rnn_bf16p8,
                                hipFuncAttributeMaxDynamicSharedMemorySize,
                                (int)ldsRebal) == hipSuccess) {
            err = hipLaunchCooperativeKernel((const void*)rnn_bf16p8,
                                             dim3(256), dim3(512), args,
                                             ldsRebal, stream);
        }
    }
    if (err != hipSuccess && ws_size >= needDec) {
        (void)hipGetLastError();
        if (hipFuncSetAttribute((const void*)rnn_decoup8,
                                hipFuncAttributeMaxDynamicSharedMemorySize,
                                (int)ldsRebal) == hipSuccess) {
            (void)hipLaunchCooperativeKernel((const void*)rnn_decoup8,
                                             dim3(256), dim3(512), args,
                                             ldsRebal, stream);
        }
    }
}